// Round 5
// baseline (181.091 us; speedup 1.0000x reference)
//
#include <hip/hip_runtime.h>
#include <stdint.h>

#define B_  32
#define M_  1024
#define DF  128   // feature dim
#define ED  64    // embedding dim

typedef __attribute__((ext_vector_type(8))) short short8;   // 8 bf16 (4 VGPRs)
typedef __attribute__((ext_vector_type(4))) short short4v;  // 4 bf16 (2 VGPRs)
typedef __attribute__((ext_vector_type(4))) float floatx4;  // MFMA C/D

__device__ inline unsigned short f2bf(float f) {
    union { float f; unsigned u; } v; v.f = f;
    unsigned r = v.u + 0x7fffu + ((v.u >> 16) & 1u);
    return (unsigned short)(r >> 16);
}

__device__ inline short8 cvt8(float4 a, float4 b) {
    short8 s;
    s[0] = (short)f2bf(a.x); s[1] = (short)f2bf(a.y);
    s[2] = (short)f2bf(a.z); s[3] = (short)f2bf(a.w);
    s[4] = (short)f2bf(b.x); s[5] = (short)f2bf(b.y);
    s[6] = (short)f2bf(b.z); s[7] = (short)f2bf(b.w);
    return s;
}

__device__ inline void load_lds16(const void* g, void* l) {
    __builtin_amdgcn_global_load_lds(
        (const __attribute__((address_space(1))) unsigned int*)g,
        (__attribute__((address_space(3))) unsigned int*)l, 16, 0, 0);
}

// ================================================================ MAIN PATH
// prep remap: XCD g = lin%8 owns sub-graphs b in [4g, 4g+4)
__device__ inline void remap_block(int& b, int& mt2) {
    int lin = blockIdx.y * 16 + blockIdx.x;
    int g = lin & 7, kk = lin >> 3;
    b = g * 4 + (kk >> 4);
    mt2 = kk & 15;
}

// ---------------------------------------------------------------- prep (verified R2):
//  dinv (full rowsums of relu(EE^T)+I via MFMA), Ebf (bf16 cast of E),
//  Xt = (dinv_n * X)^T for this block's 64 rows. No S materialization.
__global__ __launch_bounds__(256) void prep_kernel(
    const float* __restrict__ E, const float* __restrict__ X,
    unsigned short* __restrict__ Ebf, float* __restrict__ dinv,
    unsigned short* __restrict__ Xt) {
    int b, mt2; remap_block(b, mt2);
    int m0 = mt2 * 64;
    int t = threadIdx.x;
    int w = t >> 6, lane = t & 63, quad = lane >> 4, lc = lane & 15;

    __shared__ unsigned short sEn[128 * 72];  // staged E chunk (bf16); reused as sT
    __shared__ float sDinv[64];

    const float* Eb = E + (size_t)b * M_ * ED;
    unsigned short* Ebg = Ebf + (size_t)b * M_ * ED;
    int base_m = m0 + w * 16;

    short8 afr[2];
    for (int ks = 0; ks < 2; ++ks) {
        const float* p = Eb + (size_t)(base_m + lc) * ED + ks * 32 + quad * 8;
        afr[ks] = cvt8(*(const float4*)p, *(const float4*)(p + 4));
    }
    floatx4 rsum = (floatx4){0.f, 0.f, 0.f, 0.f};

    for (int nc = 0; nc < 8; ++nc) {
        __syncthreads();
        for (int it = 0; it < 4; ++it) {
            int c = t + 256 * it;             // 1024 = 128 rows x 8
            int row = c >> 3, off = (c & 7) * 8;
            const float* p = Eb + (size_t)(nc * 128 + row) * ED + off;
            *(short8*)(&sEn[row * 72 + off]) = cvt8(*(const float4*)p, *(const float4*)(p + 4));
        }
        __syncthreads();
        if ((mt2 & 7) == nc) {                // persist one chunk-half of Ebf
            int half = mt2 >> 3;
            for (int it = 0; it < 2; ++it) {
                int c = t + 256 * it;
                int row = half * 64 + (c >> 3), off = (c & 7) * 8;
                *(short8*)(Ebg + (size_t)(nc * 128 + row) * ED + off) =
                    *(const short8*)(&sEn[row * 72 + off]);
            }
        }
        for (int nt = 0; nt < 8; ++nt) {
            short8 b0 = *(const short8*)(&sEn[(nt * 16 + lc) * 72 + quad * 8]);
            short8 b1 = *(const short8*)(&sEn[(nt * 16 + lc) * 72 + 32 + quad * 8]);
            floatx4 s = (floatx4){0.f, 0.f, 0.f, 0.f};
            s = __builtin_amdgcn_mfma_f32_16x16x32_bf16(afr[0], b0, s, 0, 0, 0);
            s = __builtin_amdgcn_mfma_f32_16x16x32_bf16(afr[1], b1, s, 0, 0, 0);
            int n = nc * 128 + nt * 16 + lc;
            for (int r = 0; r < 4; ++r) {
                int m = base_m + quad * 4 + r;
                float v = fmaxf(s[r], 0.f);
                if (m == n) v += 1.0f;
                rsum[r] += v;
            }
        }
    }
    for (int r = 0; r < 4; ++r) {
        float v = rsum[r];
        v += __shfl_xor(v, 1, 16);
        v += __shfl_xor(v, 2, 16);
        v += __shfl_xor(v, 4, 16);
        v += __shfl_xor(v, 8, 16);
        if (lc == 0) {
            float dvv = rsqrtf(v);
            int mloc = w * 16 + quad * 4 + r;
            sDinv[mloc] = dvv;
            dinv[b * M_ + m0 + mloc] = dvv;
        }
    }
    __syncthreads();
    {   // tscale: Xt[d][m0..m0+64) = bf16(dinv_n * X)^T, reuse sEn as sT[128 d][72]
        int nloc = t >> 5;
        int d4 = (t & 31) * 4;
        for (int pass = 0; pass < 8; ++pass) {
            int n = pass * 8 + nloc;
            float sc = sDinv[n];
            float4 v = *(const float4*)(X + (size_t)(b * M_ + m0 + n) * DF + d4);
            sEn[(d4 + 0) * 72 + n] = f2bf(v.x * sc);
            sEn[(d4 + 1) * 72 + n] = f2bf(v.y * sc);
            sEn[(d4 + 2) * 72 + n] = f2bf(v.z * sc);
            sEn[(d4 + 3) * 72 + n] = f2bf(v.w * sc);
        }
    }
    __syncthreads();
    for (int it = 0; it < 4; ++it) {
        int c = t + 256 * it;
        int d = c >> 3, off = (c & 7) * 8;
        *(short8*)(Xt + (size_t)(b * DF + d) * M_ + m0 + off) =
            *(const short8*)(&sEn[d * 72 + off]);
    }
}

// ---------------------------------------------------------------- layer v5:
// BM=128 (8 blocks/graph, grid 256 = 1/CU), 512 threads (8 waves: 4 m-strips x 2 halves).
// Double-buffered sEn/sPW via global_load_lds; next chunk's stage ISSUED BEFORE
// current chunk's compute (T3-minimum pipeline), one drain per phase boundary.
// LDS layout (bytes):
//   0     : sEn[2][128][64] u16 (16KB each)
//   32768 : sS  [128][128]  u16 (32KB)   (epilogue: sY)
//   65536 : sPW[2][128][128] u16 (32KB each)  (epilogue: sW at buf0)
// epilogue reuse: sT [128][136] u16 @0 (MODE1) / sF [128][132] f32 @0 (MODE2)
template <int MODE>
__global__ __launch_bounds__(512, 2) void layer_kernel(
    const unsigned short* __restrict__ Ebf,   // [b][1024 n][64] bf16
    const unsigned short* __restrict__ Pt,    // [b][128 d][1024 n] bf16
    const float* __restrict__ Wf,             // [128 o][128 i] fp32
    const float* __restrict__ dinv,
    unsigned short* __restrict__ OutT,
    float* __restrict__ OutF) {
    int b = blockIdx.x, mt = blockIdx.y;      // lin%8 == b%8 -> graph pinned to XCD
    int m0 = mt * 128;
    int t = threadIdx.x;
    int w = t >> 6, lane = t & 63, quad = lane >> 4, lc = lane & 15;
    int wr = w >> 1, wc = w & 1;              // 4 m-strips x 2 halves

    __shared__ char lds[131072];
    unsigned short* sS = (unsigned short*)(lds + 32768);

    const unsigned short* Eb = Ebf + (size_t)b * M_ * ED;
    const unsigned short* Pb = Pt + (size_t)b * DF * M_;

    // E fragments for own 32 m-rows
    short8 ae[2][2];
    for (int i = 0; i < 2; ++i) {
        int row = m0 + wr * 32 + i * 16 + lc;
        for (int ks = 0; ks < 2; ++ks)
            ae[i][ks] = *(const short8*)(Eb + (size_t)row * ED + ks * 32 + quad * 8);
    }
    float dv[2][4];
    for (int i = 0; i < 2; ++i)
        for (int r = 0; r < 4; ++r)
            dv[i][r] = dinv[b * M_ + m0 + wr * 32 + i * 16 + quad * 4 + r];

    floatx4 acc[2][4];
    for (int i = 0; i < 2; ++i)
        for (int j = 0; j < 4; ++j) acc[i][j] = (floatx4){0.f, 0.f, 0.f, 0.f};

    // async stage of chunk nc into buffer sel (wave-uniform LDS dest + lane*16)
    auto stage = [&](int sel, int nc) {
        // sEn: 16 slots x 1KB (8 rows each)
        for (int r = 0; r < 2; ++r) {
            int slot = r * 8 + w;
            int te = slot * 64 + lane;
            const void* gp = Eb + (size_t)(nc * 128 + (te >> 3)) * ED + (te & 7) * 8;
            load_lds16(gp, lds + sel * 16384 + slot * 1024);
        }
        // sPW: 32 slots x 1KB (4 rows each)
        for (int r = 0; r < 4; ++r) {
            int slot = r * 8 + w;
            int te = slot * 64 + lane;
            const void* gp = Pb + (size_t)(te >> 4) * M_ + nc * 128 + (te & 15) * 8;
            load_lds16(gp, lds + 65536 + sel * 32768 + slot * 1024);
        }
    };

    int cur = 0;
    stage(0, 0);
    __syncthreads();                          // drain prologue staging

    for (int nc = 0; nc < 8; ++nc) {
        if (nc < 7) stage(cur ^ 1, nc + 1);   // prefetch BEFORE compute
        const unsigned short* sEn = (const unsigned short*)(lds + cur * 16384);
        const unsigned short* sPW = (const unsigned short*)(lds + 65536 + cur * 32768);
        // S tile: 128 m x 128 n; wave: 32 m (wr) x 64 n (wc)
        for (int jt = 0; jt < 4; ++jt) {
            int ncol = wc * 64 + jt * 16;
            short8 b0 = *(const short8*)(&sEn[(ncol + lc) * 64 + quad * 8]);
            short8 b1 = *(const short8*)(&sEn[(ncol + lc) * 64 + 32 + quad * 8]);
            for (int i = 0; i < 2; ++i) {
                floatx4 s = (floatx4){0.f, 0.f, 0.f, 0.f};
                s = __builtin_amdgcn_mfma_f32_16x16x32_bf16(ae[i][0], b0, s, 0, 0, 0);
                s = __builtin_amdgcn_mfma_f32_16x16x32_bf16(ae[i][1], b1, s, 0, 0, 0);
                int mloc = wr * 32 + i * 16 + quad * 4;
                for (int r = 0; r < 4; ++r) {
                    float v = fmaxf(s[r], 0.f);
                    if (m0 + mloc + r == nc * 128 + ncol + lc) v += 1.0f;
                    sS[(mloc + r) * 128 + ncol + lc] = f2bf(v);
                }
            }
        }
        __syncthreads();                      // sS visible to all waves
        // Z += S_tile @ Pt_tile^T (K=128); wave: 32 m (wr) x 64 d (wc)
        for (int ks = 0; ks < 4; ++ks) {
            short8 afr[2], bfr[4];
            for (int i = 0; i < 2; ++i)
                afr[i] = *(const short8*)(&sS[(wr * 32 + i * 16 + lc) * 128 + ks * 32 + quad * 8]);
            for (int j = 0; j < 4; ++j)
                bfr[j] = *(const short8*)(&sPW[(wc * 64 + j * 16 + lc) * 128 + ks * 32 + quad * 8]);
            for (int i = 0; i < 2; ++i)
                for (int j = 0; j < 4; ++j)
                    acc[i][j] = __builtin_amdgcn_mfma_f32_16x16x32_bf16(afr[i], bfr[j], acc[i][j], 0, 0, 0);
        }
        __syncthreads();                      // buf[cur] reads done; prefetch landed
        cur ^= 1;
    }

    // ---- epilogue: Y = dinv*Z (bf16) -> H = relu(Y @ W^T)
    unsigned short* sY = sS;                  // [128][128]
    unsigned short* sW = (unsigned short*)(lds + 65536);
    for (int i = 0; i < 2; ++i)
        for (int j = 0; j < 4; ++j) {
            int mrow = wr * 32 + i * 16 + quad * 4;
            int col = wc * 64 + j * 16 + lc;
            for (int r = 0; r < 4; ++r)
                sY[(mrow + r) * 128 + col] = f2bf(acc[i][j][r] * dv[i][r]);
        }
    for (int it = 0; it < 4; ++it) {          // W fp32 -> bf16 LDS
        int c = t + 512 * it;
        int row = c >> 4, off = (c & 15) * 8;
        const float* p = Wf + row * DF + off;
        *(short8*)(&sW[row * 128 + off]) = cvt8(*(const float4*)p, *(const float4*)(p + 4));
    }
    __syncthreads();
    floatx4 accH[2][4];
    for (int i = 0; i < 2; ++i)
        for (int j = 0; j < 4; ++j) accH[i][j] = (floatx4){0.f, 0.f, 0.f, 0.f};
    for (int ks = 0; ks < 4; ++ks) {
        short8 afr[2], bfr[4];
        for (int i = 0; i < 2; ++i)
            afr[i] = *(const short8*)(&sY[(wr * 32 + i * 16 + lc) * 128 + ks * 32 + quad * 8]);
        for (int j = 0; j < 4; ++j)
            bfr[j] = *(const short8*)(&sW[(wc * 64 + j * 16 + lc) * 128 + ks * 32 + quad * 8]);
        for (int i = 0; i < 2; ++i)
            for (int j = 0; j < 4; ++j)
                accH[i][j] = __builtin_amdgcn_mfma_f32_16x16x32_bf16(afr[i], bfr[j], accH[i][j], 0, 0, 0);
    }
    if (MODE == 2) {
        __syncthreads();                      // sY/sW dead; reuse lds as fp32 sF[128][132]
        float* sF = (float*)lds;
        for (int i = 0; i < 2; ++i)
            for (int j = 0; j < 4; ++j) {
                int mrow = wr * 32 + i * 16 + quad * 4;
                int col = wc * 64 + j * 16 + lc;
                for (int r = 0; r < 4; ++r)
                    sF[(mrow + r) * 132 + col] = fmaxf(accH[i][j][r], 0.f);
            }
        __syncthreads();
        float* Ob = OutF + ((size_t)b * M_ + m0) * DF;
        for (int it = 0; it < 8; ++it) {
            int c = t + 512 * it;             // 4096 = 128 rows x 32 float4
            int row = c >> 5, off = (c & 31) * 4;
            *(float4*)(Ob + (size_t)row * DF + off) = *(const float4*)(&sF[row * 132 + off]);
        }
    } else {
        __syncthreads();                      // reuse lds as sT [128 o][136] u16
        unsigned short* sT = (unsigned short*)lds;
        for (int i = 0; i < 2; ++i)
            for (int j = 0; j < 4; ++j) {
                int mrow = wr * 32 + i * 16 + quad * 4;
                int col = wc * 64 + j * 16 + lc;
                short4v pk;
                for (int r = 0; r < 4; ++r)
                    pk[r] = (short)f2bf(fmaxf(accH[i][j][r], 0.f) * dv[i][r]);
                *(short4v*)(&sT[col * 136 + mrow]) = pk;  // 8B write, mrow % 4 == 0
            }
        __syncthreads();
        for (int it = 0; it < 4; ++it) {
            int c = t + 512 * it;             // 2048 = 128 o-rows x 16
            int o = c >> 4, off = (c & 15) * 8;
            *(short8*)(OutT + (size_t)(b * DF + o) * M_ + m0 + off) =
                *(const short8*)(&sT[o * 136 + off]);
        }
    }
}

// ================================================================ fallback path (verified earlier)
__global__ __launch_bounds__(256) void cast_kernel(
    const float* __restrict__ E, const float* __restrict__ W1,
    const float* __restrict__ W2, unsigned short* __restrict__ Ebf,
    unsigned short* __restrict__ W1bf, unsigned short* __restrict__ W2bf) {
    const int NE = B_ * M_ * ED;          // 2,097,152
    const int NW = DF * DF;               // 16,384
    int idx = (blockIdx.x * 256 + threadIdx.x) * 4;
    const float* src; unsigned short* dst; int off;
    if (idx < NE)            { src = E;  dst = Ebf;  off = idx; }
    else if (idx < NE + NW)  { src = W1; dst = W1bf; off = idx - NE; }
    else                     { src = W2; dst = W2bf; off = idx - NE - NW; }
    float4 v = *(const float4*)(src + off);
    ushort4 o;
    o.x = f2bf(v.x); o.y = f2bf(v.y); o.z = f2bf(v.z); o.w = f2bf(v.w);
    *(ushort4*)(dst + off) = o;
}

__global__ __launch_bounds__(256) void degree_kernel(
    const unsigned short* __restrict__ Ebf, float* __restrict__ dinv) {
    int mt = blockIdx.x, b = blockIdx.y;
    int t = threadIdx.x;
    int w = t >> 6, lane = t & 63, quad = lane >> 4, lc = lane & 15;
    __shared__ unsigned short sEn[128][72];
    const unsigned short* Eb = Ebf + (size_t)b * M_ * ED;
    short8 afr[2][2];
    for (int i = 0; i < 2; ++i) {
        int row = mt * 128 + w * 32 + i * 16 + lc;
        for (int ks = 0; ks < 2; ++ks)
            afr[i][ks] = *(const short8*)(Eb + (size_t)row * ED + ks * 32 + quad * 8);
    }
    floatx4 rsum[2];
    rsum[0] = (floatx4){0.f,0.f,0.f,0.f};
    rsum[1] = (floatx4){0.f,0.f,0.f,0.f};
    for (int nc = 0; nc < 8; ++nc) {
        __syncthreads();
        for (int it = 0; it < 4; ++it) {
            int c = t + 256 * it;
            int row = c >> 3, off = (c & 7) * 8;
            *(short8*)(&sEn[row][off]) =
                *(const short8*)(Eb + (size_t)(nc * 128 + row) * ED + off);
        }
        __syncthreads();
        for (int nt = 0; nt < 8; ++nt) {
            short8 b0 = *(const short8*)(&sEn[nt * 16 + lc][quad * 8]);
            short8 b1 = *(const short8*)(&sEn[nt * 16 + lc][32 + quad * 8]);
            for (int i = 0; i < 2; ++i) {
                floatx4 s = (floatx4){0.f,0.f,0.f,0.f};
                s = __builtin_amdgcn_mfma_f32_16x16x32_bf16(afr[i][0], b0, s, 0, 0, 0);
                s = __builtin_amdgcn_mfma_f32_16x16x32_bf16(afr[i][1], b1, s, 0, 0, 0);
                for (int r = 0; r < 4; ++r) rsum[i][r] += fmaxf(s[r], 0.f);
            }
        }
    }
    for (int i = 0; i < 2; ++i)
        for (int r = 0; r < 4; ++r) {
            float v = rsum[i][r];
            v += __shfl_xor(v, 1, 16);
            v += __shfl_xor(v, 2, 16);
            v += __shfl_xor(v, 4, 16);
            v += __shfl_xor(v, 8, 16);
            if (lc == 0) {
                int row = mt * 128 + w * 32 + i * 16 + quad * 4 + r;
                dinv[b * M_ + row] = rsqrtf(1.0f + v);
            }
        }
}

__global__ __launch_bounds__(256) void tscale128_kernel(
    const float* __restrict__ X, const float* __restrict__ dinv,
    unsigned short* __restrict__ Xt) {
    int mt = blockIdx.x, b = blockIdx.y;
    int t = threadIdx.x;
    __shared__ unsigned short sT[128][136];
    int nloc = t >> 5;
    int d4 = (t & 31) * 4;
    for (int pass = 0; pass < 16; ++pass) {
        int n = pass * 8 + nloc;
        int grow = b * M_ + mt * 128 + n;
        float sc = dinv[grow];
        float4 v = *(const float4*)(X + (size_t)grow * DF + d4);
        sT[d4 + 0][n] = f2bf(v.x * sc);
        sT[d4 + 1][n] = f2bf(v.y * sc);
        sT[d4 + 2][n] = f2bf(v.z * sc);
        sT[d4 + 3][n] = f2bf(v.w * sc);
    }
    __syncthreads();
    for (int it = 0; it < 8; ++it) {
        int c = t + 256 * it;
        int d = c >> 4, off = (c & 15) * 8;
        *(short8*)(Xt + (size_t)(b * DF + d) * M_ + mt * 128 + off) =
            *(const short8*)(&sT[d][off]);
    }
}

template <int MODE>
__global__ __launch_bounds__(256) void gcn_kernel(
    const unsigned short* __restrict__ Ebf,
    const unsigned short* __restrict__ Pt,
    const unsigned short* __restrict__ Wbf,
    const float* __restrict__ dinv,
    unsigned short* __restrict__ OutT,
    float* __restrict__ OutF) {
    int mt = blockIdx.x, b = blockIdx.y;
    int t = threadIdx.x;
    int w = t >> 6, lane = t & 63, quad = lane >> 4, lc = lane & 15;
    int wr = w & 1, wc = w >> 1;
    __shared__ unsigned short sEn[128][72];
    __shared__ unsigned short sS[128][136];
    __shared__ unsigned short sPW[128][136];
    const unsigned short* Eb = Ebf + (size_t)b * M_ * ED;
    short8 ae[4][2];
    for (int i = 0; i < 4; ++i) {
        int row = mt * 128 + wr * 64 + i * 16 + lc;
        for (int ks = 0; ks < 2; ++ks)
            ae[i][ks] = *(const short8*)(Eb + (size_t)row * ED + ks * 32 + quad * 8);
    }
    floatx4 accZ[4][4];
    for (int i = 0; i < 4; ++i)
        for (int j = 0; j < 4; ++j) accZ[i][j] = (floatx4){0.f,0.f,0.f,0.f};
    for (int nc = 0; nc < 8; ++nc) {
        __syncthreads();
        for (int it = 0; it < 4; ++it) {
            int c = t + 256 * it;
            int row = c >> 3, off = (c & 7) * 8;
            *(short8*)(&sEn[row][off]) =
                *(const short8*)(Eb + (size_t)(nc * 128 + row) * ED + off);
        }
        for (int it = 0; it < 8; ++it) {
            int c = t + 256 * it;
            int drow = c >> 4, off = (c & 15) * 8;
            *(short8*)(&sPW[drow][off]) =
                *(const short8*)(Pt + (size_t)(b * DF + drow) * M_ + nc * 128 + off);
        }
        __syncthreads();
        for (int jt = 0; jt < 4; ++jt) {
            int ncol = wc * 64 + jt * 16;
            short8 b0 = *(const short8*)(&sEn[ncol + lc][quad * 8]);
            short8 b1 = *(const short8*)(&sEn[ncol + lc][32 + quad * 8]);
            for (int i = 0; i < 4; ++i) {
                floatx4 s = (floatx4){0.f,0.f,0.f,0.f};
                s = __builtin_amdgcn_mfma_f32_16x16x32_bf16(ae[i][0], b0, s, 0, 0, 0);
                s = __builtin_amdgcn_mfma_f32_16x16x32_bf16(ae[i][1], b1, s, 0, 0, 0);
                int mrow = wr * 64 + i * 16 + quad * 4;
                for (int r = 0; r < 4; ++r) {
                    float v = fmaxf(s[r], 0.f);
                    if (mt == nc && (mrow + r) == (ncol + lc)) v += 1.0f;
                    sS[mrow + r][ncol + lc] = f2bf(v);
                }
            }
        }
        __syncthreads();
        for (int ks = 0; ks < 4; ++ks) {
            short8 afr[4];
            for (int i = 0; i < 4; ++i)
                afr[i] = *(const short8*)(&sS[wr * 64 + i * 16 + lc][ks * 32 + quad * 8]);
            for (int j = 0; j < 4; ++j) {
                short8 bfr = *(const short8*)(&sPW[wc * 64 + j * 16 + lc][ks * 32 + quad * 8]);
                for (int i = 0; i < 4; ++i)
                    accZ[i][j] = __builtin_amdgcn_mfma_f32_16x16x32_bf16(afr[i], bfr, accZ[i][j], 0, 0, 0);
            }
        }
    }
    float dv[4][4];
    for (int i = 0; i < 4; ++i)
        for (int r = 0; r < 4; ++r)
            dv[i][r] = dinv[b * M_ + mt * 128 + wr * 64 + i * 16 + quad * 4 + r];
    __syncthreads();
    for (int i = 0; i < 4; ++i)
        for (int j = 0; j < 4; ++j) {
            int mrow = wr * 64 + i * 16 + quad * 4;
            int col = wc * 64 + j * 16 + lc;
            for (int r = 0; r < 4; ++r)
                sS[mrow + r][col] = f2bf(accZ[i][j][r] * dv[i][r]);
        }
    for (int it = 0; it < 8; ++it) {
        int c = t + 256 * it;
        int row = c >> 4, off = (c & 15) * 8;
        *(short8*)(&sPW[row][off]) = *(const short8*)(Wbf + row * DF + off);
    }
    __syncthreads();
    floatx4 accH[4][4];
    for (int i = 0; i < 4; ++i)
        for (int j = 0; j < 4; ++j) accH[i][j] = (floatx4){0.f,0.f,0.f,0.f};
    for (int ks = 0; ks < 4; ++ks) {
        short8 afr[4], bfr[4];
        for (int i = 0; i < 4; ++i)
            afr[i] = *(const short8*)(&sS[wr * 64 + i * 16 + lc][ks * 32 + quad * 8]);
        for (int j = 0; j < 4; ++j)
            bfr[j] = *(const short8*)(&sPW[wc * 64 + j * 16 + lc][ks * 32 + quad * 8]);
        for (int i = 0; i < 4; ++i)
            for (int j = 0; j < 4; ++j)
                accH[i][j] = __builtin_amdgcn_mfma_f32_16x16x32_bf16(afr[i], bfr[j], accH[i][j], 0, 0, 0);
    }
    if (MODE == 2) {
        float* Ob = OutF + ((size_t)b * M_ + mt * 128) * DF;
        for (int i = 0; i < 4; ++i)
            for (int j = 0; j < 4; ++j) {
                int mrow = wr * 64 + i * 16 + quad * 4;
                int col = wc * 64 + j * 16 + lc;
                for (int r = 0; r < 4; ++r)
                    Ob[(size_t)(mrow + r) * DF + col] = fmaxf(accH[i][j][r], 0.f);
            }
    } else {
        __syncthreads();
        for (int i = 0; i < 4; ++i)
            for (int j = 0; j < 4; ++j) {
                int mrow = wr * 64 + i * 16 + quad * 4;
                int col = wc * 64 + j * 16 + lc;
                for (int r = 0; r < 4; ++r)
                    sS[col][mrow + r] = f2bf(fmaxf(accH[i][j][r], 0.f) * dv[i][r]);
            }
        __syncthreads();
        unsigned short* Ob = OutT + (size_t)b * DF * M_ + mt * 128;
        for (int it = 0; it < 8; ++it) {
            int c = t + 256 * it;
            int orow = c >> 4, off = (c & 15) * 8;
            *(short8*)(Ob + (size_t)orow * M_ + off) = *(const short8*)(&sS[orow][off]);
        }
    }
}

// ---------------------------------------------------------------- launch
extern "C" void kernel_launch(void* const* d_in, const int* in_sizes, int n_in,
                              void* d_out, int out_size, void* d_ws, size_t ws_size,
                              hipStream_t stream) {
    (void)in_sizes; (void)n_in; (void)out_size;
    const float* X  = (const float*)d_in[0];
    const float* E  = (const float*)d_in[1];
    const float* W1 = (const float*)d_in[2];
    const float* W2 = (const float*)d_in[3];
    float* out = (float*)d_out;

    char* ws = (char*)d_ws;
    unsigned short* Ebf  = (unsigned short*)(ws);
    unsigned short* W1bf = (unsigned short*)(ws + 4194304);
    unsigned short* W2bf = (unsigned short*)(ws + 4227072);
    float*          dinv = (float*)(ws + 4259840);
    unsigned short* Xt   = (unsigned short*)(ws + 4390912);
    unsigned short* Ht   = (unsigned short*)(ws + 12779520);
    const size_t NEED = 21168128ull;

    if (ws_size >= NEED) {
        prep_kernel<<<dim3(16, 32), 256, 0, stream>>>(E, X, Ebf, dinv, Xt);
        layer_kernel<1><<<dim3(32, 8), 512, 0, stream>>>(Ebf, Xt, W1, dinv, Ht, nullptr);
        layer_kernel<2><<<dim3(32, 8), 512, 0, stream>>>(Ebf, Ht, W2, dinv, nullptr, out);
    } else {
        cast_kernel<<<2080, 256, 0, stream>>>(E, W1, W2, Ebf, W1bf, W2bf);
        degree_kernel<<<dim3(8, 32), 256, 0, stream>>>(Ebf, dinv);
        tscale128_kernel<<<dim3(8, 32), 256, 0, stream>>>(X, dinv, Xt);
        gcn_kernel<1><<<dim3(8, 32), 256, 0, stream>>>(Ebf, Xt, W1bf, dinv, Ht, nullptr);
        gcn_kernel<2><<<dim3(8, 32), 256, 0, stream>>>(Ebf, Ht, W2bf, dinv, nullptr, out);
    }
}

// Round 6
// 144.527 us; speedup vs baseline: 1.2530x; 1.2530x over previous
//
#include <hip/hip_runtime.h>
#include <stdint.h>

#define B_  32
#define M_  1024
#define DF  128   // feature dim
#define ED  64    // embedding dim

typedef __attribute__((ext_vector_type(8))) short short8;   // 8 bf16 (4 VGPRs)
typedef __attribute__((ext_vector_type(4))) short short4v;  // 4 bf16 (2 VGPRs)
typedef __attribute__((ext_vector_type(4))) float floatx4;  // MFMA C/D

__device__ inline unsigned short f2bf(float f) {
    union { float f; unsigned u; } v; v.f = f;
    unsigned r = v.u + 0x7fffu + ((v.u >> 16) & 1u);
    return (unsigned short)(r >> 16);
}

__device__ inline short8 cvt8(float4 a, float4 b) {
    short8 s;
    s[0] = (short)f2bf(a.x); s[1] = (short)f2bf(a.y);
    s[2] = (short)f2bf(a.z); s[3] = (short)f2bf(a.w);
    s[4] = (short)f2bf(b.x); s[5] = (short)f2bf(b.y);
    s[6] = (short)f2bf(b.z); s[7] = (short)f2bf(b.w);
    return s;
}

__device__ inline void load_lds16(const void* g, void* l) {
    __builtin_amdgcn_global_load_lds(
        (const __attribute__((address_space(1))) unsigned int*)g,
        (__attribute__((address_space(3))) unsigned int*)l, 16, 0, 0);
}

// G4 XOR swizzle on the column byte within a row (bits 4-6; involution).
#define SWZ(colb, row) ((colb) ^ (((row) & 7) << 4))

// ================================================================ MAIN PATH
// prep remap: XCD g = lin%8 owns sub-graphs b in [4g, 4g+4)
__device__ inline void remap_block(int& b, int& mt2) {
    int lin = blockIdx.y * 16 + blockIdx.x;
    int g = lin & 7, kk = lin >> 3;
    b = g * 4 + (kk >> 4);
    mt2 = kk & 15;
}

// ---------------------------------------------------------------- prep (verified R2):
//  dinv (full rowsums of relu(EE^T)+I via MFMA), Ebf (bf16 cast of E),
//  Xt = (dinv_n * X)^T for this block's 64 rows. No S materialization.
__global__ __launch_bounds__(256) void prep_kernel(
    const float* __restrict__ E, const float* __restrict__ X,
    unsigned short* __restrict__ Ebf, float* __restrict__ dinv,
    unsigned short* __restrict__ Xt) {
    int b, mt2; remap_block(b, mt2);
    int m0 = mt2 * 64;
    int t = threadIdx.x;
    int w = t >> 6, lane = t & 63, quad = lane >> 4, lc = lane & 15;

    __shared__ unsigned short sEn[128 * 72];  // staged E chunk (bf16); reused as sT
    __shared__ float sDinv[64];

    const float* Eb = E + (size_t)b * M_ * ED;
    unsigned short* Ebg = Ebf + (size_t)b * M_ * ED;
    int base_m = m0 + w * 16;

    short8 afr[2];
    for (int ks = 0; ks < 2; ++ks) {
        const float* p = Eb + (size_t)(base_m + lc) * ED + ks * 32 + quad * 8;
        afr[ks] = cvt8(*(const float4*)p, *(const float4*)(p + 4));
    }
    floatx4 rsum = (floatx4){0.f, 0.f, 0.f, 0.f};

    for (int nc = 0; nc < 8; ++nc) {
        __syncthreads();
        for (int it = 0; it < 4; ++it) {
            int c = t + 256 * it;             // 1024 = 128 rows x 8
            int row = c >> 3, off = (c & 7) * 8;
            const float* p = Eb + (size_t)(nc * 128 + row) * ED + off;
            *(short8*)(&sEn[row * 72 + off]) = cvt8(*(const float4*)p, *(const float4*)(p + 4));
        }
        __syncthreads();
        if ((mt2 & 7) == nc) {                // persist one chunk-half of Ebf
            int half = mt2 >> 3;
            for (int it = 0; it < 2; ++it) {
                int c = t + 256 * it;
                int row = half * 64 + (c >> 3), off = (c & 7) * 8;
                *(short8*)(Ebg + (size_t)(nc * 128 + row) * ED + off) =
                    *(const short8*)(&sEn[row * 72 + off]);
            }
        }
        for (int nt = 0; nt < 8; ++nt) {
            short8 b0 = *(const short8*)(&sEn[(nt * 16 + lc) * 72 + quad * 8]);
            short8 b1 = *(const short8*)(&sEn[(nt * 16 + lc) * 72 + 32 + quad * 8]);
            floatx4 s = (floatx4){0.f, 0.f, 0.f, 0.f};
            s = __builtin_amdgcn_mfma_f32_16x16x32_bf16(afr[0], b0, s, 0, 0, 0);
            s = __builtin_amdgcn_mfma_f32_16x16x32_bf16(afr[1], b1, s, 0, 0, 0);
            int n = nc * 128 + nt * 16 + lc;
            for (int r = 0; r < 4; ++r) {
                int m = base_m + quad * 4 + r;
                float v = fmaxf(s[r], 0.f);
                if (m == n) v += 1.0f;
                rsum[r] += v;
            }
        }
    }
    for (int r = 0; r < 4; ++r) {
        float v = rsum[r];
        v += __shfl_xor(v, 1, 16);
        v += __shfl_xor(v, 2, 16);
        v += __shfl_xor(v, 4, 16);
        v += __shfl_xor(v, 8, 16);
        if (lc == 0) {
            float dvv = rsqrtf(v);
            int mloc = w * 16 + quad * 4 + r;
            sDinv[mloc] = dvv;
            dinv[b * M_ + m0 + mloc] = dvv;
        }
    }
    __syncthreads();
    {   // tscale: Xt[d][m0..m0+64) = bf16(dinv_n * X)^T, reuse sEn as sT[128 d][72]
        int nloc = t >> 5;
        int d4 = (t & 31) * 4;
        for (int pass = 0; pass < 8; ++pass) {
            int n = pass * 8 + nloc;
            float sc = sDinv[n];
            float4 v = *(const float4*)(X + (size_t)(b * M_ + m0 + n) * DF + d4);
            sEn[(d4 + 0) * 72 + n] = f2bf(v.x * sc);
            sEn[(d4 + 1) * 72 + n] = f2bf(v.y * sc);
            sEn[(d4 + 2) * 72 + n] = f2bf(v.z * sc);
            sEn[(d4 + 3) * 72 + n] = f2bf(v.w * sc);
        }
    }
    __syncthreads();
    for (int it = 0; it < 4; ++it) {
        int c = t + 256 * it;
        int d = c >> 3, off = (c & 7) * 8;
        *(short8*)(Xt + (size_t)(b * DF + d) * M_ + m0 + off) =
            *(const short8*)(&sEn[d * 72 + off]);
    }
}

// ---------------------------------------------------------------- layer v6:
// v5 structure (BM=128, 8 waves, double-buffered global_load_lds prefetch)
// + rule-#21 XOR swizzle: LDS dest linear, global SOURCE pre-swizzled,
//   reads apply the same XOR -> all fragment reads <=2-way conflicts.
// LDS layout (bytes):
//   0     : sEn[2][128 rows x 128B]  (16KB each)
//   32768 : sS  [128 rows x 256B]    (32KB)   (epilogue: sY)
//   65536 : sPW[2][128 rows x 256B]  (32KB each)  (epilogue: sW at buf0)
// epilogue reuse: sT [128][136] u16 @0 (MODE1) / sF [128][132] f32 @0 (MODE2)
template <int MODE>
__global__ __launch_bounds__(512, 2) void layer_kernel(
    const unsigned short* __restrict__ Ebf,   // [b][1024 n][64] bf16
    const unsigned short* __restrict__ Pt,    // [b][128 d][1024 n] bf16
    const float* __restrict__ Wf,             // [128 o][128 i] fp32
    const float* __restrict__ dinv,
    unsigned short* __restrict__ OutT,
    float* __restrict__ OutF) {
    int b = blockIdx.x, mt = blockIdx.y;      // lin%8 == b%8 -> graph pinned to XCD
    int m0 = mt * 128;
    int t = threadIdx.x;
    int w = t >> 6, lane = t & 63, quad = lane >> 4, lc = lane & 15;
    int wr = w >> 1, wc = w & 1;              // 4 m-strips x 2 halves

    __shared__ char lds[131072];

    const unsigned short* Eb = Ebf + (size_t)b * M_ * ED;
    const unsigned short* Pb = Pt + (size_t)b * DF * M_;

    // E fragments for own 32 m-rows
    short8 ae[2][2];
    for (int i = 0; i < 2; ++i) {
        int row = m0 + wr * 32 + i * 16 + lc;
        for (int ks = 0; ks < 2; ++ks)
            ae[i][ks] = *(const short8*)(Eb + (size_t)row * ED + ks * 32 + quad * 8);
    }
    float dv[2][4];
    for (int i = 0; i < 2; ++i)
        for (int r = 0; r < 4; ++r)
            dv[i][r] = dinv[b * M_ + m0 + wr * 32 + i * 16 + quad * 4 + r];

    floatx4 acc[2][4];
    for (int i = 0; i < 2; ++i)
        for (int j = 0; j < 4; ++j) acc[i][j] = (floatx4){0.f, 0.f, 0.f, 0.f};

    // async stage of chunk nc into buffer sel; LDS dest LINEAR (wave-uniform
    // base + lane*16), global source column pre-swizzled (involution).
    int srcColE = ((lane & 7) ^ (lane >> 3)) * 8;                 // elements
    int srcColP = ((lane & 15) ^ ((w & 1) * 4 + (lane >> 4))) * 8;
    auto stage = [&](int sel, int nc) {
        for (int r = 0; r < 2; ++r) {         // sEn: 16 slots x 1KB (8 rows)
            int slot = r * 8 + w;
            int row = slot * 8 + (lane >> 3);
            const void* gp = Eb + (size_t)(nc * 128 + row) * ED + srcColE;
            load_lds16(gp, lds + sel * 16384 + slot * 1024);
        }
        for (int r = 0; r < 4; ++r) {         // sPW: 32 slots x 1KB (4 rows)
            int slot = r * 8 + w;
            int row = slot * 4 + (lane >> 4);
            const void* gp = Pb + (size_t)row * M_ + nc * 128 + srcColP;
            load_lds16(gp, lds + 65536 + sel * 32768 + slot * 1024);
        }
    };

    int cur = 0;
    stage(0, 0);
    __syncthreads();                          // drain prologue staging

    for (int nc = 0; nc < 8; ++nc) {
        if (nc < 7) stage(cur ^ 1, nc + 1);   // prefetch BEFORE compute
        const char* sEnB = lds + cur * 16384;
        const char* sPWB = lds + 65536 + cur * 32768;
        char* sSB = lds + 32768;
        // S tile: 128 m x 128 n; wave: 32 m (wr) x 64 n (wc)
        for (int jt = 0; jt < 4; ++jt) {
            int ncol = wc * 64 + jt * 16;
            int nrow = ncol + lc;
            short8 b0 = *(const short8*)(sEnB + nrow * 128 + SWZ(quad * 16, nrow));
            short8 b1 = *(const short8*)(sEnB + nrow * 128 + SWZ(64 + quad * 16, nrow));
            for (int i = 0; i < 2; ++i) {
                floatx4 s = (floatx4){0.f, 0.f, 0.f, 0.f};
                s = __builtin_amdgcn_mfma_f32_16x16x32_bf16(ae[i][0], b0, s, 0, 0, 0);
                s = __builtin_amdgcn_mfma_f32_16x16x32_bf16(ae[i][1], b1, s, 0, 0, 0);
                int mloc = wr * 32 + i * 16 + quad * 4;
                for (int r = 0; r < 4; ++r) {
                    float v = fmaxf(s[r], 0.f);
                    if (m0 + mloc + r == nc * 128 + ncol + lc) v += 1.0f;
                    int mrow = mloc + r;
                    *(unsigned short*)(sSB + mrow * 256 + SWZ(2 * (ncol + lc), mrow)) = f2bf(v);
                }
            }
        }
        __syncthreads();                      // sS visible; prefetch drained
        // Z += S_tile @ Pt_tile^T (K=128); wave: 32 m (wr) x 64 d (wc)
        for (int ks = 0; ks < 4; ++ks) {
            short8 afr[2], bfr[4];
            for (int i = 0; i < 2; ++i) {
                int row = wr * 32 + i * 16 + lc;
                afr[i] = *(const short8*)(sSB + row * 256 + SWZ(ks * 64 + quad * 16, row));
            }
            for (int j = 0; j < 4; ++j) {
                int row = wc * 64 + j * 16 + lc;
                bfr[j] = *(const short8*)(sPWB + row * 256 + SWZ(ks * 64 + quad * 16, row));
            }
            for (int i = 0; i < 2; ++i)
                for (int j = 0; j < 4; ++j)
                    acc[i][j] = __builtin_amdgcn_mfma_f32_16x16x32_bf16(afr[i], bfr[j], acc[i][j], 0, 0, 0);
        }
        __syncthreads();                      // buf[cur] reads done
        cur ^= 1;
    }

    // ---- epilogue: Y = dinv*Z (bf16) -> H = relu(Y @ W^T)  (swizzled sY/sW)
    char* sYB = lds + 32768;
    char* sWB = lds + 65536;
    for (int i = 0; i < 2; ++i)
        for (int j = 0; j < 4; ++j) {
            int mloc = wr * 32 + i * 16 + quad * 4;
            int col = wc * 64 + j * 16 + lc;
            for (int r = 0; r < 4; ++r) {
                int mrow = mloc + r;
                *(unsigned short*)(sYB + mrow * 256 + SWZ(2 * col, mrow)) =
                    f2bf(acc[i][j][r] * dv[i][r]);
            }
        }
    for (int it = 0; it < 4; ++it) {          // W fp32 -> bf16 LDS (swizzled write)
        int c = t + 512 * it;
        int row = c >> 4, colb = (c & 15) * 16;
        const float* p = Wf + row * DF + (c & 15) * 8;
        *(short8*)(sWB + row * 256 + SWZ(colb, row)) =
            cvt8(*(const float4*)p, *(const float4*)(p + 4));
    }
    __syncthreads();
    floatx4 accH[2][4];
    for (int i = 0; i < 2; ++i)
        for (int j = 0; j < 4; ++j) accH[i][j] = (floatx4){0.f, 0.f, 0.f, 0.f};
    for (int ks = 0; ks < 4; ++ks) {
        short8 afr[2], bfr[4];
        for (int i = 0; i < 2; ++i) {
            int row = wr * 32 + i * 16 + lc;
            afr[i] = *(const short8*)(sYB + row * 256 + SWZ(ks * 64 + quad * 16, row));
        }
        for (int j = 0; j < 4; ++j) {
            int row = wc * 64 + j * 16 + lc;
            bfr[j] = *(const short8*)(sWB + row * 256 + SWZ(ks * 64 + quad * 16, row));
        }
        for (int i = 0; i < 2; ++i)
            for (int j = 0; j < 4; ++j)
                accH[i][j] = __builtin_amdgcn_mfma_f32_16x16x32_bf16(afr[i], bfr[j], accH[i][j], 0, 0, 0);
    }
    if (MODE == 2) {
        __syncthreads();                      // sY/sW dead; reuse lds as fp32 sF[128][132]
        float* sF = (float*)lds;
        for (int i = 0; i < 2; ++i)
            for (int j = 0; j < 4; ++j) {
                int mrow = wr * 32 + i * 16 + quad * 4;
                int col = wc * 64 + j * 16 + lc;
                for (int r = 0; r < 4; ++r)
                    sF[(mrow + r) * 132 + col] = fmaxf(accH[i][j][r], 0.f);
            }
        __syncthreads();
        float* Ob = OutF + ((size_t)b * M_ + m0) * DF;
        for (int it = 0; it < 8; ++it) {
            int c = t + 512 * it;             // 4096 = 128 rows x 32 float4
            int row = c >> 5, off = (c & 31) * 4;
            *(float4*)(Ob + (size_t)row * DF + off) = *(const float4*)(&sF[row * 132 + off]);
        }
    } else {
        __syncthreads();                      // reuse lds as sT [128 o][136] u16
        unsigned short* sT = (unsigned short*)lds;
        for (int i = 0; i < 2; ++i)
            for (int j = 0; j < 4; ++j) {
                int mrow = wr * 32 + i * 16 + quad * 4;
                int col = wc * 64 + j * 16 + lc;
                short4v pk;
                for (int r = 0; r < 4; ++r)
                    pk[r] = (short)f2bf(fmaxf(accH[i][j][r], 0.f) * dv[i][r]);
                *(short4v*)(&sT[col * 136 + mrow]) = pk;  // 8B write, mrow % 4 == 0
            }
        __syncthreads();
        for (int it = 0; it < 4; ++it) {
            int c = t + 512 * it;             // 2048 = 128 o-rows x 16
            int o = c >> 4, off = (c & 15) * 8;
            *(short8*)(OutT + (size_t)(b * DF + o) * M_ + m0 + off) =
                *(const short8*)(&sT[o * 136 + off]);
        }
    }
}

// ================================================================ fallback path (verified earlier)
__global__ __launch_bounds__(256) void cast_kernel(
    const float* __restrict__ E, const float* __restrict__ W1,
    const float* __restrict__ W2, unsigned short* __restrict__ Ebf,
    unsigned short* __restrict__ W1bf, unsigned short* __restrict__ W2bf) {
    const int NE = B_ * M_ * ED;          // 2,097,152
    const int NW = DF * DF;               // 16,384
    int idx = (blockIdx.x * 256 + threadIdx.x) * 4;
    const float* src; unsigned short* dst; int off;
    if (idx < NE)            { src = E;  dst = Ebf;  off = idx; }
    else if (idx < NE + NW)  { src = W1; dst = W1bf; off = idx - NE; }
    else                     { src = W2; dst = W2bf; off = idx - NE - NW; }
    float4 v = *(const float4*)(src + off);
    ushort4 o;
    o.x = f2bf(v.x); o.y = f2bf(v.y); o.z = f2bf(v.z); o.w = f2bf(v.w);
    *(ushort4*)(dst + off) = o;
}

__global__ __launch_bounds__(256) void degree_kernel(
    const unsigned short* __restrict__ Ebf, float* __restrict__ dinv) {
    int mt = blockIdx.x, b = blockIdx.y;
    int t = threadIdx.x;
    int w = t >> 6, lane = t & 63, quad = lane >> 4, lc = lane & 15;
    __shared__ unsigned short sEn[128][72];
    const unsigned short* Eb = Ebf + (size_t)b * M_ * ED;
    short8 afr[2][2];
    for (int i = 0; i < 2; ++i) {
        int row = mt * 128 + w * 32 + i * 16 + lc;
        for (int ks = 0; ks < 2; ++ks)
            afr[i][ks] = *(const short8*)(Eb + (size_t)row * ED + ks * 32 + quad * 8);
    }
    floatx4 rsum[2];
    rsum[0] = (floatx4){0.f,0.f,0.f,0.f};
    rsum[1] = (floatx4){0.f,0.f,0.f,0.f};
    for (int nc = 0; nc < 8; ++nc) {
        __syncthreads();
        for (int it = 0; it < 4; ++it) {
            int c = t + 256 * it;
            int row = c >> 3, off = (c & 7) * 8;
            *(short8*)(&sEn[row][off]) =
                *(const short8*)(Eb + (size_t)(nc * 128 + row) * ED + off);
        }
        __syncthreads();
        for (int nt = 0; nt < 8; ++nt) {
            short8 b0 = *(const short8*)(&sEn[nt * 16 + lc][quad * 8]);
            short8 b1 = *(const short8*)(&sEn[nt * 16 + lc][32 + quad * 8]);
            for (int i = 0; i < 2; ++i) {
                floatx4 s = (floatx4){0.f,0.f,0.f,0.f};
                s = __builtin_amdgcn_mfma_f32_16x16x32_bf16(afr[i][0], b0, s, 0, 0, 0);
                s = __builtin_amdgcn_mfma_f32_16x16x32_bf16(afr[i][1], b1, s, 0, 0, 0);
                for (int r = 0; r < 4; ++r) rsum[i][r] += fmaxf(s[r], 0.f);
            }
        }
    }
    for (int i = 0; i < 2; ++i)
        for (int r = 0; r < 4; ++r) {
            float v = rsum[i][r];
            v += __shfl_xor(v, 1, 16);
            v += __shfl_xor(v, 2, 16);
            v += __shfl_xor(v, 4, 16);
            v += __shfl_xor(v, 8, 16);
            if (lc == 0) {
                int row = mt * 128 + w * 32 + i * 16 + quad * 4 + r;
                dinv[b * M_ + row] = rsqrtf(1.0f + v);
            }
        }
}

__global__ __launch_bounds__(256) void tscale128_kernel(
    const float* __restrict__ X, const float* __restrict__ dinv,
    unsigned short* __restrict__ Xt) {
    int mt = blockIdx.x, b = blockIdx.y;
    int t = threadIdx.x;
    __shared__ unsigned short sT[128][136];
    int nloc = t >> 5;
    int d4 = (t & 31) * 4;
    for (int pass = 0; pass < 16; ++pass) {
        int n = pass * 8 + nloc;
        int grow = b * M_ + mt * 128 + n;
        float sc = dinv[grow];
        float4 v = *(const float4*)(X + (size_t)grow * DF + d4);
        sT[d4 + 0][n] = f2bf(v.x * sc);
        sT[d4 + 1][n] = f2bf(v.y * sc);
        sT[d4 + 2][n] = f2bf(v.z * sc);
        sT[d4 + 3][n] = f2bf(v.w * sc);
    }
    __syncthreads();
    for (int it = 0; it < 8; ++it) {
        int c = t + 256 * it;
        int d = c >> 4, off = (c & 15) * 8;
        *(short8*)(Xt + (size_t)(b * DF + d) * M_ + mt * 128 + off) =
            *(const short8*)(&sT[d][off]);
    }
}

template <int MODE>
__global__ __launch_bounds__(256) void gcn_kernel(
    const unsigned short* __restrict__ Ebf,
    const unsigned short* __restrict__ Pt,
    const unsigned short* __restrict__ Wbf,
    const float* __restrict__ dinv,
    unsigned short* __restrict__ OutT,
    float* __restrict__ OutF) {
    int mt = blockIdx.x, b = blockIdx.y;
    int t = threadIdx.x;
    int w = t >> 6, lane = t & 63, quad = lane >> 4, lc = lane & 15;
    int wr = w & 1, wc = w >> 1;
    __shared__ unsigned short sEn[128][72];
    __shared__ unsigned short sS[128][136];
    __shared__ unsigned short sPW[128][136];
    const unsigned short* Eb = Ebf + (size_t)b * M_ * ED;
    short8 ae[4][2];
    for (int i = 0; i < 4; ++i) {
        int row = mt * 128 + wr * 64 + i * 16 + lc;
        for (int ks = 0; ks < 2; ++ks)
            ae[i][ks] = *(const short8*)(Eb + (size_t)row * ED + ks * 32 + quad * 8);
    }
    floatx4 accZ[4][4];
    for (int i = 0; i < 4; ++i)
        for (int j = 0; j < 4; ++j) accZ[i][j] = (floatx4){0.f,0.f,0.f,0.f};
    for (int nc = 0; nc < 8; ++nc) {
        __syncthreads();
        for (int it = 0; it < 4; ++it) {
            int c = t + 256 * it;
            int row = c >> 3, off = (c & 7) * 8;
            *(short8*)(&sEn[row][off]) =
                *(const short8*)(Eb + (size_t)(nc * 128 + row) * ED + off);
        }
        for (int it = 0; it < 8; ++it) {
            int c = t + 256 * it;
            int drow = c >> 4, off = (c & 15) * 8;
            *(short8*)(&sPW[drow][off]) =
                *(const short8*)(Pt + (size_t)(b * DF + drow) * M_ + nc * 128 + off);
        }
        __syncthreads();
        for (int jt = 0; jt < 4; ++jt) {
            int ncol = wc * 64 + jt * 16;
            short8 b0 = *(const short8*)(&sEn[ncol + lc][quad * 8]);
            short8 b1 = *(const short8*)(&sEn[ncol + lc][32 + quad * 8]);
            for (int i = 0; i < 4; ++i) {
                floatx4 s = (floatx4){0.f,0.f,0.f,0.f};
                s = __builtin_amdgcn_mfma_f32_16x16x32_bf16(ae[i][0], b0, s, 0, 0, 0);
                s = __builtin_amdgcn_mfma_f32_16x16x32_bf16(ae[i][1], b1, s, 0, 0, 0);
                int mrow = wr * 64 + i * 16 + quad * 4;
                for (int r = 0; r < 4; ++r) {
                    float v = fmaxf(s[r], 0.f);
                    if (mt == nc && (mrow + r) == (ncol + lc)) v += 1.0f;
                    sS[mrow + r][ncol + lc] = f2bf(v);
                }
            }
        }
        __syncthreads();
        for (int ks = 0; ks < 4; ++ks) {
            short8 afr[4];
            for (int i = 0; i < 4; ++i)
                afr[i] = *(const short8*)(&sS[wr * 64 + i * 16 + lc][ks * 32 + quad * 8]);
            for (int j = 0; j < 4; ++j) {
                short8 bfr = *(const short8*)(&sPW[wc * 64 + j * 16 + lc][ks * 32 + quad * 8]);
                for (int i = 0; i < 4; ++i)
                    accZ[i][j] = __builtin_amdgcn_mfma_f32_16x16x32_bf16(afr[i], bfr, accZ[i][j], 0, 0, 0);
            }
        }
    }
    float dv[4][4];
    for (int i = 0; i < 4; ++i)
        for (int r = 0; r < 4; ++r)
            dv[i][r] = dinv[b * M_ + mt * 128 + wr * 64 + i * 16 + quad * 4 + r];
    __syncthreads();
    for (int i = 0; i < 4; ++i)
        for (int j = 0; j < 4; ++j) {
            int mrow = wr * 64 + i * 16 + quad * 4;
            int col = wc * 64 + j * 16 + lc;
            for (int r = 0; r < 4; ++r)
                sS[mrow + r][col] = f2bf(accZ[i][j][r] * dv[i][r]);
        }
    for (int it = 0; it < 8; ++it) {
        int c = t + 256 * it;
        int row = c >> 4, off = (c & 15) * 8;
        *(short8*)(&sPW[row][off]) = *(const short8*)(Wbf + row * DF + off);
    }
    __syncthreads();
    floatx4 accH[4][4];
    for (int i = 0; i < 4; ++i)
        for (int j = 0; j < 4; ++j) accH[i][j] = (floatx4){0.f,0.f,0.f,0.f};
    for (int ks = 0; ks < 4; ++ks) {
        short8 afr[4], bfr[4];
        for (int i = 0; i < 4; ++i)
            afr[i] = *(const short8*)(&sS[wr * 64 + i * 16 + lc][ks * 32 + quad * 8]);
        for (int j = 0; j < 4; ++j)
            bfr[j] = *(const short8*)(&sPW[wc * 64 + j * 16 + lc][ks * 32 + quad * 8]);
        for (int i = 0; i < 4; ++i)
            for (int j = 0; j < 4; ++j)
                accH[i][j] = __builtin_amdgcn_mfma_f32_16x16x32_bf16(afr[i], bfr[j], accH[i][j], 0, 0, 0);
    }
    if (MODE == 2) {
        float* Ob = OutF + ((size_t)b * M_ + mt * 128) * DF;
        for (int i = 0; i < 4; ++i)
            for (int j = 0; j < 4; ++j) {
                int mrow = wr * 64 + i * 16 + quad * 4;
                int col = wc * 64 + j * 16 + lc;
                for (int r = 0; r < 4; ++r)
                    Ob[(size_t)(mrow + r) * DF + col] = fmaxf(accH[i][j][r], 0.f);
            }
    } else {
        __syncthreads();
        for (int i = 0; i < 4; ++i)
            for (int j = 0; j < 4; ++j) {
                int mrow = wr * 64 + i * 16 + quad * 4;
                int col = wc * 64 + j * 16 + lc;
                for (int r = 0; r < 4; ++r)
                    sS[col][mrow + r] = f2bf(fmaxf(accH[i][j][r], 0.f) * dv[i][r]);
            }
        __syncthreads();
        unsigned short* Ob = OutT + (size_t)b * DF * M_ + mt * 128;
        for (int it = 0; it < 8; ++it) {
            int c = t + 256 * it;
            int orow = c >> 4, off = (c & 15) * 8;
            *(short8*)(Ob + (size_t)orow * M_ + off) = *(const short8*)(&sS[orow][off]);
        }
    }
}

// ---------------------------------------------------------------- launch
extern "C" void kernel_launch(void* const* d_in, const int* in_sizes, int n_in,
                              void* d_out, int out_size, void* d_ws, size_t ws_size,
                              hipStream_t stream) {
    (void)in_sizes; (void)n_in; (void)out_size;
    const float* X  = (const float*)d_in[0];
    const float* E  = (const float*)d_in[1];
    const float* W1 = (const float*)d_in[2];
    const float* W2 = (const float*)d_in[3];
    float* out = (float*)d_out;

    char* ws = (char*)d_ws;
    unsigned short* Ebf  = (unsigned short*)(ws);
    unsigned short* W1bf = (unsigned short*)(ws + 4194304);
    unsigned short* W2bf = (unsigned short*)(ws + 4227072);
    float*          dinv = (float*)(ws + 4259840);
    unsigned short* Xt   = (unsigned short*)(ws + 4390912);
    unsigned short* Ht   = (unsigned short*)(ws + 12779520);
    const size_t NEED = 21168128ull;

    if (ws_size >= NEED) {
        prep_kernel<<<dim3(16, 32), 256, 0, stream>>>(E, X, Ebf, dinv, Xt);
        layer_kernel<1><<<dim3(32, 8), 512, 0, stream>>>(Ebf, Xt, W1, dinv, Ht, nullptr);
        layer_kernel<2><<<dim3(32, 8), 512, 0, stream>>>(Ebf, Ht, W2, dinv, nullptr, out);
    } else {
        cast_kernel<<<2080, 256, 0, stream>>>(E, W1, W2, Ebf, W1bf, W2bf);
        degree_kernel<<<dim3(8, 32), 256, 0, stream>>>(Ebf, dinv);
        tscale128_kernel<<<dim3(8, 32), 256, 0, stream>>>(X, dinv, Xt);
        gcn_kernel<1><<<dim3(8, 32), 256, 0, stream>>>(Ebf, Xt, W1bf, dinv, Ht, nullptr);
        gcn_kernel<2><<<dim3(8, 32), 256, 0, stream>>>(Ebf, Ht, W2bf, dinv, nullptr, out);
    }
}

// Round 7
// 141.621 us; speedup vs baseline: 1.2787x; 1.0205x over previous
//
#include <hip/hip_runtime.h>
#include <stdint.h>

#define B_  32
#define M_  1024
#define DF  128   // feature dim
#define ED  64    // embedding dim

typedef __attribute__((ext_vector_type(8))) short short8;   // 8 bf16 (4 VGPRs)
typedef __attribute__((ext_vector_type(4))) short short4v;  // 4 bf16 (2 VGPRs)
typedef __attribute__((ext_vector_type(4))) float floatx4;  // MFMA C/D

__device__ inline unsigned short f2bf(float f) {
    union { float f; unsigned u; } v; v.f = f;
    unsigned r = v.u + 0x7fffu + ((v.u >> 16) & 1u);
    return (unsigned short)(r >> 16);
}

__device__ inline short8 cvt8(float4 a, float4 b) {
    short8 s;
    s[0] = (short)f2bf(a.x); s[1] = (short)f2bf(a.y);
    s[2] = (short)f2bf(a.z); s[3] = (short)f2bf(a.w);
    s[4] = (short)f2bf(b.x); s[5] = (short)f2bf(b.y);
    s[6] = (short)f2bf(b.z); s[7] = (short)f2bf(b.w);
    return s;
}

__device__ inline void load_lds16(const void* g, void* l) {
    __builtin_amdgcn_global_load_lds(
        (const __attribute__((address_space(1))) unsigned int*)g,
        (__attribute__((address_space(3))) unsigned int*)l, 16, 0, 0);
}

// raw workgroup barrier: LDS-visibility only, does NOT drain vmcnt
// (keeps global_load_lds prefetch in flight across the barrier).
__device__ inline void barrier_lds_only() {
    asm volatile("s_waitcnt lgkmcnt(0)" ::: "memory");
    __builtin_amdgcn_sched_barrier(0);
    __builtin_amdgcn_s_barrier();
    __builtin_amdgcn_sched_barrier(0);
}

// G4 XOR swizzle on the column byte within a row (bits 4-6; involution).
#define SWZ(colb, row) ((colb) ^ (((row) & 7) << 4))

// ================================================================ MAIN PATH

// ---------------------------------------------------------------- prep v7:
// BM=128 (grid 32 x 8: graph b pinned to XCD b%8, SAME pinning as layers),
// 512 threads. Reg-prefetched fp32 staging (loads in flight across raw
// barriers). Computes dinv (full rowsums, same accumulation order), persists
// Ebf (block mt persists chunk nc==mt), and Xt for its own 128 rows.
__global__ __launch_bounds__(512) void prep_kernel(
    const float* __restrict__ E, const float* __restrict__ X,
    unsigned short* __restrict__ Ebf, float* __restrict__ dinv,
    unsigned short* __restrict__ Xt) {
    int b = blockIdx.x, mt = blockIdx.y;
    int m0 = mt * 128;
    int t = threadIdx.x;
    int w = t >> 6, lane = t & 63, quad = lane >> 4, lc = lane & 15;

    __shared__ unsigned short sBuf[128 * 136]; // E stage view: stride 72; sT view: stride 136
    __shared__ float sDinv[128];

    const float* Eb = E + (size_t)b * M_ * ED;
    unsigned short* Ebg = Ebf + (size_t)b * M_ * ED;
    int base_m = m0 + w * 16;

    // A-fragments: rows base_m + lc, cast fp32 -> bf16 in flight
    short8 afr[2];
    for (int ks = 0; ks < 2; ++ks) {
        const float* p = Eb + (size_t)(base_m + lc) * ED + ks * 32 + quad * 8;
        afr[ks] = cvt8(*(const float4*)p, *(const float4*)(p + 4));
    }
    floatx4 rsum = (floatx4){0.f, 0.f, 0.f, 0.f};

    // register prefetch: 2 slots x (2 float4) per thread per chunk
    float4 pre[4];
    auto ldreg = [&](int nc) {
        for (int it = 0; it < 2; ++it) {
            int c = t + 512 * it;             // 1024 = 128 rows x 8
            const float* p = Eb + (size_t)(nc * 128 + (c >> 3)) * ED + (c & 7) * 8;
            pre[it * 2]     = *(const float4*)p;
            pre[it * 2 + 1] = *(const float4*)(p + 4);
        }
    };
    ldreg(0);

    for (int nc = 0; nc < 8; ++nc) {
        // write prefetched regs -> LDS (cast)
        for (int it = 0; it < 2; ++it) {
            int c = t + 512 * it;
            *(short8*)(&sBuf[(c >> 3) * 72 + (c & 7) * 8]) = cvt8(pre[it * 2], pre[it * 2 + 1]);
        }
        if (nc < 7) ldreg(nc + 1);            // issue next chunk's loads (overlap compute)
        barrier_lds_only();                   // sBuf visible; reg loads stay in flight
        if (mt == nc) {                       // persist this chunk of Ebf
            for (int it = 0; it < 2; ++it) {
                int c = t + 512 * it;
                int row = c >> 3, off = (c & 7) * 8;
                *(short8*)(Ebg + (size_t)(nc * 128 + row) * ED + off) =
                    *(const short8*)(&sBuf[row * 72 + off]);
            }
        }
        for (int nt = 0; nt < 8; ++nt) {
            short8 b0 = *(const short8*)(&sBuf[(nt * 16 + lc) * 72 + quad * 8]);
            short8 b1 = *(const short8*)(&sBuf[(nt * 16 + lc) * 72 + 32 + quad * 8]);
            floatx4 s = (floatx4){0.f, 0.f, 0.f, 0.f};
            s = __builtin_amdgcn_mfma_f32_16x16x32_bf16(afr[0], b0, s, 0, 0, 0);
            s = __builtin_amdgcn_mfma_f32_16x16x32_bf16(afr[1], b1, s, 0, 0, 0);
            int n = nc * 128 + nt * 16 + lc;
            for (int r = 0; r < 4; ++r) {
                int m = base_m + quad * 4 + r;
                float v = fmaxf(s[r], 0.f);
                if (m == n) v += 1.0f;
                rsum[r] += v;
            }
        }
        barrier_lds_only();                   // sBuf reads done before next overwrite
    }
    // dinv for own 128 rows
    for (int r = 0; r < 4; ++r) {
        float v = rsum[r];
        v += __shfl_xor(v, 1, 16);
        v += __shfl_xor(v, 2, 16);
        v += __shfl_xor(v, 4, 16);
        v += __shfl_xor(v, 8, 16);
        if (lc == 0) {
            float dvv = rsqrtf(v);
            int mloc = w * 16 + quad * 4 + r;
            sDinv[mloc] = dvv;
            dinv[b * M_ + m0 + mloc] = dvv;
        }
    }
    __syncthreads();                          // sDinv ready; sBuf reads done
    // tscale: Xt[b][d][m0..m0+128) = bf16(dinv_n * X)^T, sBuf as sT[128 d][136]
    {
        int nloc = t >> 5;                    // 0..15
        int d4 = (t & 31) * 4;
        for (int pass = 0; pass < 8; ++pass) {
            int n = pass * 16 + nloc;         // local row 0..127
            float sc = sDinv[n];
            float4 v = *(const float4*)(X + (size_t)(b * M_ + m0 + n) * DF + d4);
            sBuf[(d4 + 0) * 136 + n] = f2bf(v.x * sc);
            sBuf[(d4 + 1) * 136 + n] = f2bf(v.y * sc);
            sBuf[(d4 + 2) * 136 + n] = f2bf(v.z * sc);
            sBuf[(d4 + 3) * 136 + n] = f2bf(v.w * sc);
        }
    }
    __syncthreads();
    for (int it = 0; it < 4; ++it) {
        int c = t + 512 * it;                 // 2048 = 128 d-rows x 16
        int d = c >> 4, off = (c & 15) * 8;
        *(short8*)(Xt + (size_t)(b * DF + d) * M_ + m0 + off) =
            *(const short8*)(&sBuf[d * 136 + off]);
    }
}

// ---------------------------------------------------------------- layer v7:
// v6 (BM=128, 8 waves, dbuf global_load_lds prefetch, rule-#21 swizzle)
// + mid-chunk barrier is now LDS-only (raw s_barrier + lgkmcnt(0)):
//   the 6 prefetch loads stay in flight across the ENTIRE chunk and drain
//   only at the end-of-chunk __syncthreads, where they're actually needed.
// LDS layout (bytes):
//   0     : sEn[2][128 rows x 128B]  (16KB each)
//   32768 : sS  [128 rows x 256B]    (32KB)   (epilogue: sY)
//   65536 : sPW[2][128 rows x 256B]  (32KB each)  (epilogue: sW at buf0)
template <int MODE>
__global__ __launch_bounds__(512, 2) void layer_kernel(
    const unsigned short* __restrict__ Ebf,   // [b][1024 n][64] bf16
    const unsigned short* __restrict__ Pt,    // [b][128 d][1024 n] bf16
    const float* __restrict__ Wf,             // [128 o][128 i] fp32
    const float* __restrict__ dinv,
    unsigned short* __restrict__ OutT,
    float* __restrict__ OutF) {
    int b = blockIdx.x, mt = blockIdx.y;      // graph b pinned to XCD b%8
    int m0 = mt * 128;
    int t = threadIdx.x;
    int w = t >> 6, lane = t & 63, quad = lane >> 4, lc = lane & 15;
    int wr = w >> 1, wc = w & 1;              // 4 m-strips x 2 halves

    __shared__ char lds[131072];

    const unsigned short* Eb = Ebf + (size_t)b * M_ * ED;
    const unsigned short* Pb = Pt + (size_t)b * DF * M_;

    // E fragments for own 32 m-rows
    short8 ae[2][2];
    for (int i = 0; i < 2; ++i) {
        int row = m0 + wr * 32 + i * 16 + lc;
        for (int ks = 0; ks < 2; ++ks)
            ae[i][ks] = *(const short8*)(Eb + (size_t)row * ED + ks * 32 + quad * 8);
    }
    float dv[2][4];
    for (int i = 0; i < 2; ++i)
        for (int r = 0; r < 4; ++r)
            dv[i][r] = dinv[b * M_ + m0 + wr * 32 + i * 16 + quad * 4 + r];

    floatx4 acc[2][4];
    for (int i = 0; i < 2; ++i)
        for (int j = 0; j < 4; ++j) acc[i][j] = (floatx4){0.f, 0.f, 0.f, 0.f};

    // async stage of chunk nc into buffer sel; LDS dest LINEAR (wave-uniform
    // base + lane*16), global source column pre-swizzled (involution).
    int srcColE = ((lane & 7) ^ (lane >> 3)) * 8;                 // elements
    int srcColP = ((lane & 15) ^ ((w & 1) * 4 + (lane >> 4))) * 8;
    auto stage = [&](int sel, int nc) {
        for (int r = 0; r < 2; ++r) {         // sEn: 16 slots x 1KB (8 rows)
            int slot = r * 8 + w;
            int row = slot * 8 + (lane >> 3);
            const void* gp = Eb + (size_t)(nc * 128 + row) * ED + srcColE;
            load_lds16(gp, lds + sel * 16384 + slot * 1024);
        }
        for (int r = 0; r < 4; ++r) {         // sPW: 32 slots x 1KB (4 rows)
            int slot = r * 8 + w;
            int row = slot * 4 + (lane >> 4);
            const void* gp = Pb + (size_t)row * M_ + nc * 128 + srcColP;
            load_lds16(gp, lds + 65536 + sel * 32768 + slot * 1024);
        }
    };

    int cur = 0;
    stage(0, 0);
    __syncthreads();                          // drain prologue staging

    for (int nc = 0; nc < 8; ++nc) {
        if (nc < 7) stage(cur ^ 1, nc + 1);   // prefetch BEFORE compute
        const char* sEnB = lds + cur * 16384;
        const char* sPWB = lds + 65536 + cur * 32768;
        char* sSB = lds + 32768;
        // S tile: 128 m x 128 n; wave: 32 m (wr) x 64 n (wc)
        for (int jt = 0; jt < 4; ++jt) {
            int ncol = wc * 64 + jt * 16;
            int nrow = ncol + lc;
            short8 b0 = *(const short8*)(sEnB + nrow * 128 + SWZ(quad * 16, nrow));
            short8 b1 = *(const short8*)(sEnB + nrow * 128 + SWZ(64 + quad * 16, nrow));
            for (int i = 0; i < 2; ++i) {
                floatx4 s = (floatx4){0.f, 0.f, 0.f, 0.f};
                s = __builtin_amdgcn_mfma_f32_16x16x32_bf16(ae[i][0], b0, s, 0, 0, 0);
                s = __builtin_amdgcn_mfma_f32_16x16x32_bf16(ae[i][1], b1, s, 0, 0, 0);
                int mloc = wr * 32 + i * 16 + quad * 4;
                for (int r = 0; r < 4; ++r) {
                    float v = fmaxf(s[r], 0.f);
                    if (m0 + mloc + r == nc * 128 + ncol + lc) v += 1.0f;
                    int mrow = mloc + r;
                    *(unsigned short*)(sSB + mrow * 256 + SWZ(2 * (ncol + lc), mrow)) = f2bf(v);
                }
            }
        }
        barrier_lds_only();                   // sS visible; prefetch stays in flight
        // Z += S_tile @ Pt_tile^T (K=128); wave: 32 m (wr) x 64 d (wc)
        for (int ks = 0; ks < 4; ++ks) {
            short8 afr[2], bfr[4];
            for (int i = 0; i < 2; ++i) {
                int row = wr * 32 + i * 16 + lc;
                afr[i] = *(const short8*)(sSB + row * 256 + SWZ(ks * 64 + quad * 16, row));
            }
            for (int j = 0; j < 4; ++j) {
                int row = wc * 64 + j * 16 + lc;
                bfr[j] = *(const short8*)(sPWB + row * 256 + SWZ(ks * 64 + quad * 16, row));
            }
            for (int i = 0; i < 2; ++i)
                for (int j = 0; j < 4; ++j)
                    acc[i][j] = __builtin_amdgcn_mfma_f32_16x16x32_bf16(afr[i], bfr[j], acc[i][j], 0, 0, 0);
        }
        __syncthreads();                      // drain prefetch + all LDS reads
        cur ^= 1;
    }

    // ---- epilogue: Y = dinv*Z (bf16) -> H = relu(Y @ W^T)  (swizzled sY/sW)
    char* sYB = lds + 32768;
    char* sWB = lds + 65536;
    for (int i = 0; i < 2; ++i)
        for (int j = 0; j < 4; ++j) {
            int mloc = wr * 32 + i * 16 + quad * 4;
            int col = wc * 64 + j * 16 + lc;
            for (int r = 0; r < 4; ++r) {
                int mrow = mloc + r;
                *(unsigned short*)(sYB + mrow * 256 + SWZ(2 * col, mrow)) =
                    f2bf(acc[i][j][r] * dv[i][r]);
            }
        }
    for (int it = 0; it < 4; ++it) {          // W fp32 -> bf16 LDS (swizzled write)
        int c = t + 512 * it;
        int row = c >> 4, colb = (c & 15) * 16;
        const float* p = Wf + row * DF + (c & 15) * 8;
        *(short8*)(sWB + row * 256 + SWZ(colb, row)) =
            cvt8(*(const float4*)p, *(const float4*)(p + 4));
    }
    __syncthreads();
    floatx4 accH[2][4];
    for (int i = 0; i < 2; ++i)
        for (int j = 0; j < 4; ++j) accH[i][j] = (floatx4){0.f, 0.f, 0.f, 0.f};
    for (int ks = 0; ks < 4; ++ks) {
        short8 afr[2], bfr[4];
        for (int i = 0; i < 2; ++i) {
            int row = wr * 32 + i * 16 + lc;
            afr[i] = *(const short8*)(sYB + row * 256 + SWZ(ks * 64 + quad * 16, row));
        }
        for (int j = 0; j < 4; ++j) {
            int row = wc * 64 + j * 16 + lc;
            bfr[j] = *(const short8*)(sWB + row * 256 + SWZ(ks * 64 + quad * 16, row));
        }
        for (int i = 0; i < 2; ++i)
            for (int j = 0; j < 4; ++j)
                accH[i][j] = __builtin_amdgcn_mfma_f32_16x16x32_bf16(afr[i], bfr[j], accH[i][j], 0, 0, 0);
    }
    if (MODE == 2) {
        __syncthreads();                      // sY/sW dead; reuse lds as fp32 sF[128][132]
        float* sF = (float*)lds;
        for (int i = 0; i < 2; ++i)
            for (int j = 0; j < 4; ++j) {
                int mrow = wr * 32 + i * 16 + quad * 4;
                int col = wc * 64 + j * 16 + lc;
                for (int r = 0; r < 4; ++r)
                    sF[(mrow + r) * 132 + col] = fmaxf(accH[i][j][r], 0.f);
            }
        __syncthreads();
        float* Ob = OutF + ((size_t)b * M_ + m0) * DF;
        for (int it = 0; it < 8; ++it) {
            int c = t + 512 * it;             // 4096 = 128 rows x 32 float4
            int row = c >> 5, off = (c & 31) * 4;
            *(float4*)(Ob + (size_t)row * DF + off) = *(const float4*)(&sF[row * 132 + off]);
        }
    } else {
        __syncthreads();                      // reuse lds as sT [128 o][136] u16
        unsigned short* sT = (unsigned short*)lds;
        for (int i = 0; i < 2; ++i)
            for (int j = 0; j < 4; ++j) {
                int mrow = wr * 32 + i * 16 + quad * 4;
                int col = wc * 64 + j * 16 + lc;
                short4v pk;
                for (int r = 0; r < 4; ++r)
                    pk[r] = (short)f2bf(fmaxf(accH[i][j][r], 0.f) * dv[i][r]);
                *(short4v*)(&sT[col * 136 + mrow]) = pk;  // 8B write, mrow % 4 == 0
            }
        __syncthreads();
        for (int it = 0; it < 4; ++it) {
            int c = t + 512 * it;             // 2048 = 128 o-rows x 16
            int o = c >> 4, off = (c & 15) * 8;
            *(short8*)(OutT + (size_t)(b * DF + o) * M_ + m0 + off) =
                *(const short8*)(&sT[o * 136 + off]);
        }
    }
}

// ================================================================ fallback path (verified earlier)
__global__ __launch_bounds__(256) void cast_kernel(
    const float* __restrict__ E, const float* __restrict__ W1,
    const float* __restrict__ W2, unsigned short* __restrict__ Ebf,
    unsigned short* __restrict__ W1bf, unsigned short* __restrict__ W2bf) {
    const int NE = B_ * M_ * ED;          // 2,097,152
    const int NW = DF * DF;               // 16,384
    int idx = (blockIdx.x * 256 + threadIdx.x) * 4;
    const float* src; unsigned short* dst; int off;
    if (idx < NE)            { src = E;  dst = Ebf;  off = idx; }
    else if (idx < NE + NW)  { src = W1; dst = W1bf; off = idx - NE; }
    else                     { src = W2; dst = W2bf; off = idx - NE - NW; }
    float4 v = *(const float4*)(src + off);
    ushort4 o;
    o.x = f2bf(v.x); o.y = f2bf(v.y); o.z = f2bf(v.z); o.w = f2bf(v.w);
    *(ushort4*)(dst + off) = o;
}

__global__ __launch_bounds__(256) void degree_kernel(
    const unsigned short* __restrict__ Ebf, float* __restrict__ dinv) {
    int mt = blockIdx.x, b = blockIdx.y;
    int t = threadIdx.x;
    int w = t >> 6, lane = t & 63, quad = lane >> 4, lc = lane & 15;
    __shared__ unsigned short sEn[128][72];
    const unsigned short* Eb = Ebf + (size_t)b * M_ * ED;
    short8 afr[2][2];
    for (int i = 0; i < 2; ++i) {
        int row = mt * 128 + w * 32 + i * 16 + lc;
        for (int ks = 0; ks < 2; ++ks)
            afr[i][ks] = *(const short8*)(Eb + (size_t)row * ED + ks * 32 + quad * 8);
    }
    floatx4 rsum[2];
    rsum[0] = (floatx4){0.f,0.f,0.f,0.f};
    rsum[1] = (floatx4){0.f,0.f,0.f,0.f};
    for (int nc = 0; nc < 8; ++nc) {
        __syncthreads();
        for (int it = 0; it < 4; ++it) {
            int c = t + 256 * it;
            int row = c >> 3, off = (c & 7) * 8;
            *(short8*)(&sEn[row][off]) =
                *(const short8*)(Eb + (size_t)(nc * 128 + row) * ED + off);
        }
        __syncthreads();
        for (int nt = 0; nt < 8; ++nt) {
            short8 b0 = *(const short8*)(&sEn[nt * 16 + lc][quad * 8]);
            short8 b1 = *(const short8*)(&sEn[nt * 16 + lc][32 + quad * 8]);
            for (int i = 0; i < 2; ++i) {
                floatx4 s = (floatx4){0.f,0.f,0.f,0.f};
                s = __builtin_amdgcn_mfma_f32_16x16x32_bf16(afr[i][0], b0, s, 0, 0, 0);
                s = __builtin_amdgcn_mfma_f32_16x16x32_bf16(afr[i][1], b1, s, 0, 0, 0);
                for (int r = 0; r < 4; ++r) rsum[i][r] += fmaxf(s[r], 0.f);
            }
        }
    }
    for (int i = 0; i < 2; ++i)
        for (int r = 0; r < 4; ++r) {
            float v = rsum[i][r];
            v += __shfl_xor(v, 1, 16);
            v += __shfl_xor(v, 2, 16);
            v += __shfl_xor(v, 4, 16);
            v += __shfl_xor(v, 8, 16);
            if (lc == 0) {
                int row = mt * 128 + w * 32 + i * 16 + quad * 4 + r;
                dinv[b * M_ + row] = rsqrtf(1.0f + v);
            }
        }
}

__global__ __launch_bounds__(256) void tscale128_kernel(
    const float* __restrict__ X, const float* __restrict__ dinv,
    unsigned short* __restrict__ Xt) {
    int mt = blockIdx.x, b = blockIdx.y;
    int t = threadIdx.x;
    __shared__ unsigned short sT[128][136];
    int nloc = t >> 5;
    int d4 = (t & 31) * 4;
    for (int pass = 0; pass < 16; ++pass) {
        int n = pass * 8 + nloc;
        int grow = b * M_ + mt * 128 + n;
        float sc = dinv[grow];
        float4 v = *(const float4*)(X + (size_t)grow * DF + d4);
        sT[d4 + 0][n] = f2bf(v.x * sc);
        sT[d4 + 1][n] = f2bf(v.y * sc);
        sT[d4 + 2][n] = f2bf(v.z * sc);
        sT[d4 + 3][n] = f2bf(v.w * sc);
    }
    __syncthreads();
    for (int it = 0; it < 8; ++it) {
        int c = t + 256 * it;
        int d = c >> 4, off = (c & 15) * 8;
        *(short8*)(Xt + (size_t)(b * DF + d) * M_ + mt * 128 + off) =
            *(const short8*)(&sT[d][off]);
    }
}

template <int MODE>
__global__ __launch_bounds__(256) void gcn_kernel(
    const unsigned short* __restrict__ Ebf,
    const unsigned short* __restrict__ Pt,
    const unsigned short* __restrict__ Wbf,
    const float* __restrict__ dinv,
    unsigned short* __restrict__ OutT,
    float* __restrict__ OutF) {
    int mt = blockIdx.x, b = blockIdx.y;
    int t = threadIdx.x;
    int w = t >> 6, lane = t & 63, quad = lane >> 4, lc = lane & 15;
    int wr = w & 1, wc = w >> 1;
    __shared__ unsigned short sEn[128][72];
    __shared__ unsigned short sS[128][136];
    __shared__ unsigned short sPW[128][136];
    const unsigned short* Eb = Ebf + (size_t)b * M_ * ED;
    short8 ae[4][2];
    for (int i = 0; i < 4; ++i) {
        int row = mt * 128 + wr * 64 + i * 16 + lc;
        for (int ks = 0; ks < 2; ++ks)
            ae[i][ks] = *(const short8*)(Eb + (size_t)row * ED + ks * 32 + quad * 8);
    }
    floatx4 accZ[4][4];
    for (int i = 0; i < 4; ++i)
        for (int j = 0; j < 4; ++j) accZ[i][j] = (floatx4){0.f,0.f,0.f,0.f};
    for (int nc = 0; nc < 8; ++nc) {
        __syncthreads();
        for (int it = 0; it < 4; ++it) {
            int c = t + 256 * it;
            int row = c >> 3, off = (c & 7) * 8;
            *(short8*)(&sEn[row][off]) =
                *(const short8*)(Eb + (size_t)(nc * 128 + row) * ED + off);
        }
        for (int it = 0; it < 8; ++it) {
            int c = t + 256 * it;
            int drow = c >> 4, off = (c & 15) * 8;
            *(short8*)(&sPW[drow][off]) =
                *(const short8*)(Pt + (size_t)(b * DF + drow) * M_ + nc * 128 + off);
        }
        __syncthreads();
        for (int jt = 0; jt < 4; ++jt) {
            int ncol = wc * 64 + jt * 16;
            short8 b0 = *(const short8*)(&sEn[ncol + lc][quad * 8]);
            short8 b1 = *(const short8*)(&sEn[ncol + lc][32 + quad * 8]);
            for (int i = 0; i < 4; ++i) {
                floatx4 s = (floatx4){0.f,0.f,0.f,0.f};
                s = __builtin_amdgcn_mfma_f32_16x16x32_bf16(ae[i][0], b0, s, 0, 0, 0);
                s = __builtin_amdgcn_mfma_f32_16x16x32_bf16(ae[i][1], b1, s, 0, 0, 0);
                int mrow = wr * 64 + i * 16 + quad * 4;
                for (int r = 0; r < 4; ++r) {
                    float v = fmaxf(s[r], 0.f);
                    if (mt == nc && (mrow + r) == (ncol + lc)) v += 1.0f;
                    sS[mrow + r][ncol + lc] = f2bf(v);
                }
            }
        }
        __syncthreads();
        for (int ks = 0; ks < 4; ++ks) {
            short8 afr[4];
            for (int i = 0; i < 4; ++i)
                afr[i] = *(const short8*)(&sS[wr * 64 + i * 16 + lc][ks * 32 + quad * 8]);
            for (int j = 0; j < 4; ++j) {
                short8 bfr = *(const short8*)(&sPW[wc * 64 + j * 16 + lc][ks * 32 + quad * 8]);
                for (int i = 0; i < 4; ++i)
                    accZ[i][j] = __builtin_amdgcn_mfma_f32_16x16x32_bf16(afr[i], bfr, accZ[i][j], 0, 0, 0);
            }
        }
    }
    float dv[4][4];
    for (int i = 0; i < 4; ++i)
        for (int r = 0; r < 4; ++r)
            dv[i][r] = dinv[b * M_ + mt * 128 + wr * 64 + i * 16 + quad * 4 + r];
    __syncthreads();
    for (int i = 0; i < 4; ++i)
        for (int j = 0; j < 4; ++j) {
            int mrow = wr * 64 + i * 16 + quad * 4;
            int col = wc * 64 + j * 16 + lc;
            for (int r = 0; r < 4; ++r)
                sS[mrow + r][col] = f2bf(accZ[i][j][r] * dv[i][r]);
        }
    for (int it = 0; it < 8; ++it) {
        int c = t + 256 * it;
        int row = c >> 4, off = (c & 15) * 8;
        *(short8*)(&sPW[row][off]) = *(const short8*)(Wbf + row * DF + off);
    }
    __syncthreads();
    floatx4 accH[4][4];
    for (int i = 0; i < 4; ++i)
        for (int j = 0; j < 4; ++j) accH[i][j] = (floatx4){0.f,0.f,0.f,0.f};
    for (int ks = 0; ks < 4; ++ks) {
        short8 afr[4], bfr[4];
        for (int i = 0; i < 4; ++i)
            afr[i] = *(const short8*)(&sS[wr * 64 + i * 16 + lc][ks * 32 + quad * 8]);
        for (int j = 0; j < 4; ++j)
            bfr[j] = *(const short8*)(&sPW[wc * 64 + j * 16 + lc][ks * 32 + quad * 8]);
        for (int i = 0; i < 4; ++i)
            for (int j = 0; j < 4; ++j)
                accH[i][j] = __builtin_amdgcn_mfma_f32_16x16x32_bf16(afr[i], bfr[j], accH[i][j], 0, 0, 0);
    }
    if (MODE == 2) {
        float* Ob = OutF + ((size_t)b * M_ + mt * 128) * DF;
        for (int i = 0; i < 4; ++i)
            for (int j = 0; j < 4; ++j) {
                int mrow = wr * 64 + i * 16 + quad * 4;
                int col = wc * 64 + j * 16 + lc;
                for (int r = 0; r < 4; ++r)
                    Ob[(size_t)(mrow + r) * DF + col] = fmaxf(accH[i][j][r], 0.f);
            }
    } else {
        __syncthreads();
        for (int i = 0; i < 4; ++i)
            for (int j = 0; j < 4; ++j) {
                int mrow = wr * 64 + i * 16 + quad * 4;
                int col = wc * 64 + j * 16 + lc;
                for (int r = 0; r < 4; ++r)
                    sS[col][mrow + r] = f2bf(fmaxf(accH[i][j][r], 0.f) * dv[i][r]);
            }
        __syncthreads();
        unsigned short* Ob = OutT + (size_t)b * DF * M_ + mt * 128;
        for (int it = 0; it < 8; ++it) {
            int c = t + 256 * it;
            int orow = c >> 4, off = (c & 15) * 8;
            *(short8*)(Ob + (size_t)orow * M_ + off) = *(const short8*)(&sS[orow][off]);
        }
    }
}

// ---------------------------------------------------------------- launch
extern "C" void kernel_launch(void* const* d_in, const int* in_sizes, int n_in,
                              void* d_out, int out_size, void* d_ws, size_t ws_size,
                              hipStream_t stream) {
    (void)in_sizes; (void)n_in; (void)out_size;
    const float* X  = (const float*)d_in[0];
    const float* E  = (const float*)d_in[1];
    const float* W1 = (const float*)d_in[2];
    const float* W2 = (const float*)d_in[3];
    float* out = (float*)d_out;

    char* ws = (char*)d_ws;
    unsigned short* Ebf  = (unsigned short*)(ws);
    unsigned short* W1bf = (unsigned short*)(ws + 4194304);
    unsigned short* W2bf = (unsigned short*)(ws + 4227072);
    float*          dinv = (float*)(ws + 4259840);
    unsigned short* Xt   = (unsigned short*)(ws + 4390912);
    unsigned short* Ht   = (unsigned short*)(ws + 12779520);
    const size_t NEED = 21168128ull;

    if (ws_size >= NEED) {
        prep_kernel<<<dim3(32, 8), 512, 0, stream>>>(E, X, Ebf, dinv, Xt);
        layer_kernel<1><<<dim3(32, 8), 512, 0, stream>>>(Ebf, Xt, W1, dinv, Ht, nullptr);
        layer_kernel<2><<<dim3(32, 8), 512, 0, stream>>>(Ebf, Ht, W2, dinv, nullptr, out);
    } else {
        cast_kernel<<<2080, 256, 0, stream>>>(E, W1, W2, Ebf, W1bf, W2bf);
        degree_kernel<<<dim3(8, 32), 256, 0, stream>>>(Ebf, dinv);
        tscale128_kernel<<<dim3(8, 32), 256, 0, stream>>>(X, dinv, Xt);
        gcn_kernel<1><<<dim3(8, 32), 256, 0, stream>>>(Ebf, Xt, W1bf, dinv, Ht, nullptr);
        gcn_kernel<2><<<dim3(8, 32), 256, 0, stream>>>(Ebf, Ht, W2bf, dinv, nullptr, out);
    }
}

// Round 8
// 140.291 us; speedup vs baseline: 1.2908x; 1.0095x over previous
//
#include <hip/hip_runtime.h>
#include <stdint.h>

#define B_  32
#define M_  1024
#define DF  128   // feature dim
#define ED  64    // embedding dim

typedef __attribute__((ext_vector_type(8))) short short8;   // 8 bf16 (4 VGPRs)
typedef __attribute__((ext_vector_type(4))) short short4v;  // 4 bf16 (2 VGPRs)
typedef __attribute__((ext_vector_type(4))) float floatx4;  // MFMA C/D

__device__ inline unsigned short f2bf(float f) {
    union { float f; unsigned u; } v; v.f = f;
    unsigned r = v.u + 0x7fffu + ((v.u >> 16) & 1u);
    return (unsigned short)(r >> 16);
}

__device__ inline short8 cvt8(float4 a, float4 b) {
    short8 s;
    s[0] = (short)f2bf(a.x); s[1] = (short)f2bf(a.y);
    s[2] = (short)f2bf(a.z); s[3] = (short)f2bf(a.w);
    s[4] = (short)f2bf(b.x); s[5] = (short)f2bf(b.y);
    s[6] = (short)f2bf(b.z); s[7] = (short)f2bf(b.w);
    return s;
}

__device__ inline void load_lds16(const void* g, void* l) {
    __builtin_amdgcn_global_load_lds(
        (const __attribute__((address_space(1))) unsigned int*)g,
        (__attribute__((address_space(3))) unsigned int*)l, 16, 0, 0);
}

// raw workgroup barrier: LDS-visibility only, does NOT drain vmcnt
__device__ inline void barrier_lds_only() {
    asm volatile("s_waitcnt lgkmcnt(0)" ::: "memory");
    __builtin_amdgcn_sched_barrier(0);
    __builtin_amdgcn_s_barrier();
    __builtin_amdgcn_sched_barrier(0);
}

// G4 XOR swizzle on the column byte within a row (bits 4-6; involution).
#define SWZ(colb, row) ((colb) ^ (((row) & 7) << 4))

// ================================================================ MAIN PATH

// ---------------------------------------------------------------- prep (v7, verified):
__global__ __launch_bounds__(512) void prep_kernel(
    const float* __restrict__ E, const float* __restrict__ X,
    unsigned short* __restrict__ Ebf, float* __restrict__ dinv,
    unsigned short* __restrict__ Xt) {
    int b = blockIdx.x, mt = blockIdx.y;
    int m0 = mt * 128;
    int t = threadIdx.x;
    int w = t >> 6, lane = t & 63, quad = lane >> 4, lc = lane & 15;

    __shared__ unsigned short sBuf[128 * 136];
    __shared__ float sDinv[128];

    const float* Eb = E + (size_t)b * M_ * ED;
    unsigned short* Ebg = Ebf + (size_t)b * M_ * ED;
    int base_m = m0 + w * 16;

    short8 afr[2];
    for (int ks = 0; ks < 2; ++ks) {
        const float* p = Eb + (size_t)(base_m + lc) * ED + ks * 32 + quad * 8;
        afr[ks] = cvt8(*(const float4*)p, *(const float4*)(p + 4));
    }
    floatx4 rsum = (floatx4){0.f, 0.f, 0.f, 0.f};

    float4 pre[4];
    auto ldreg = [&](int nc) {
        for (int it = 0; it < 2; ++it) {
            int c = t + 512 * it;
            const float* p = Eb + (size_t)(nc * 128 + (c >> 3)) * ED + (c & 7) * 8;
            pre[it * 2]     = *(const float4*)p;
            pre[it * 2 + 1] = *(const float4*)(p + 4);
        }
    };
    ldreg(0);

    for (int nc = 0; nc < 8; ++nc) {
        for (int it = 0; it < 2; ++it) {
            int c = t + 512 * it;
            *(short8*)(&sBuf[(c >> 3) * 72 + (c & 7) * 8]) = cvt8(pre[it * 2], pre[it * 2 + 1]);
        }
        if (nc < 7) ldreg(nc + 1);
        barrier_lds_only();
        if (mt == nc) {
            for (int it = 0; it < 2; ++it) {
                int c = t + 512 * it;
                int row = c >> 3, off = (c & 7) * 8;
                *(short8*)(Ebg + (size_t)(nc * 128 + row) * ED + off) =
                    *(const short8*)(&sBuf[row * 72 + off]);
            }
        }
        for (int nt = 0; nt < 8; ++nt) {
            short8 b0 = *(const short8*)(&sBuf[(nt * 16 + lc) * 72 + quad * 8]);
            short8 b1 = *(const short8*)(&sBuf[(nt * 16 + lc) * 72 + 32 + quad * 8]);
            floatx4 s = (floatx4){0.f, 0.f, 0.f, 0.f};
            s = __builtin_amdgcn_mfma_f32_16x16x32_bf16(afr[0], b0, s, 0, 0, 0);
            s = __builtin_amdgcn_mfma_f32_16x16x32_bf16(afr[1], b1, s, 0, 0, 0);
            int n = nc * 128 + nt * 16 + lc;
            for (int r = 0; r < 4; ++r) {
                int m = base_m + quad * 4 + r;
                float v = fmaxf(s[r], 0.f);
                if (m == n) v += 1.0f;
                rsum[r] += v;
            }
        }
        barrier_lds_only();
    }
    for (int r = 0; r < 4; ++r) {
        float v = rsum[r];
        v += __shfl_xor(v, 1, 16);
        v += __shfl_xor(v, 2, 16);
        v += __shfl_xor(v, 4, 16);
        v += __shfl_xor(v, 8, 16);
        if (lc == 0) {
            float dvv = rsqrtf(v);
            int mloc = w * 16 + quad * 4 + r;
            sDinv[mloc] = dvv;
            dinv[b * M_ + m0 + mloc] = dvv;
        }
    }
    __syncthreads();
    {
        int nloc = t >> 5;
        int d4 = (t & 31) * 4;
        for (int pass = 0; pass < 8; ++pass) {
            int n = pass * 16 + nloc;
            float sc = sDinv[n];
            float4 v = *(const float4*)(X + (size_t)(b * M_ + m0 + n) * DF + d4);
            sBuf[(d4 + 0) * 136 + n] = f2bf(v.x * sc);
            sBuf[(d4 + 1) * 136 + n] = f2bf(v.y * sc);
            sBuf[(d4 + 2) * 136 + n] = f2bf(v.z * sc);
            sBuf[(d4 + 3) * 136 + n] = f2bf(v.w * sc);
        }
    }
    __syncthreads();
    for (int it = 0; it < 4; ++it) {
        int c = t + 512 * it;
        int d = c >> 4, off = (c & 15) * 8;
        *(short8*)(Xt + (size_t)(b * DF + d) * M_ + m0 + off) =
            *(const short8*)(&sBuf[d * 136 + off]);
    }
}

// ---------------------------------------------------------------- layer v8:
// v7 + operand-swapped MFMAs for packed LDS stores (bitwise-identical values):
//  * S-build: mfma(E_n, E_m) -> lane holds 4 consecutive n of one m-row
//    -> single 8B packed S store (8 ds_write/chunk instead of 32).
//  * Z: mfma(Pt, S) -> acc = Z^T; Pt frags preloaded BEFORE the mid barrier.
//  * Y epilogue packed 8B; MODE2 accH swapped -> packed 16B fp32 stores.
template <int MODE>
__global__ __launch_bounds__(512, 2) void layer_kernel(
    const unsigned short* __restrict__ Ebf,   // [b][1024 n][64] bf16
    const unsigned short* __restrict__ Pt,    // [b][128 d][1024 n] bf16
    const float* __restrict__ Wf,             // [128 o][128 i] fp32
    const float* __restrict__ dinv,
    unsigned short* __restrict__ OutT,
    float* __restrict__ OutF) {
    int b = blockIdx.x, mt = blockIdx.y;      // graph b pinned to XCD b%8
    int m0 = mt * 128;
    int t = threadIdx.x;
    int w = t >> 6, lane = t & 63, quad = lane >> 4, lc = lane & 15;
    int wr = w >> 1, wc = w & 1;              // 4 m-strips x 2 halves

    __shared__ char lds[131072];

    const unsigned short* Eb = Ebf + (size_t)b * M_ * ED;
    const unsigned short* Pb = Pt + (size_t)b * DF * M_;

    short8 ae[2][2];
    for (int i = 0; i < 2; ++i) {
        int row = m0 + wr * 32 + i * 16 + lc;
        for (int ks = 0; ks < 2; ++ks)
            ae[i][ks] = *(const short8*)(Eb + (size_t)row * ED + ks * 32 + quad * 8);
    }
    float dv[2][4], dvm[2];
    for (int i = 0; i < 2; ++i) {
        for (int r = 0; r < 4; ++r)
            dv[i][r] = dinv[b * M_ + m0 + wr * 32 + i * 16 + quad * 4 + r];
        dvm[i] = dinv[b * M_ + m0 + wr * 32 + i * 16 + lc];
    }

    floatx4 acc[2][4];
    for (int i = 0; i < 2; ++i)
        for (int j = 0; j < 4; ++j) acc[i][j] = (floatx4){0.f, 0.f, 0.f, 0.f};

    int srcColE = ((lane & 7) ^ (lane >> 3)) * 8;
    int srcColP = ((lane & 15) ^ ((w & 1) * 4 + (lane >> 4))) * 8;
    auto stage = [&](int sel, int nc) {
        for (int r = 0; r < 2; ++r) {
            int slot = r * 8 + w;
            int row = slot * 8 + (lane >> 3);
            const void* gp = Eb + (size_t)(nc * 128 + row) * ED + srcColE;
            load_lds16(gp, lds + sel * 16384 + slot * 1024);
        }
        for (int r = 0; r < 4; ++r) {
            int slot = r * 8 + w;
            int row = slot * 4 + (lane >> 4);
            const void* gp = Pb + (size_t)row * M_ + nc * 128 + srcColP;
            load_lds16(gp, lds + 65536 + sel * 32768 + slot * 1024);
        }
    };

    int cur = 0;
    stage(0, 0);
    __syncthreads();                          // drain prologue staging

    for (int nc = 0; nc < 8; ++nc) {
        if (nc < 7) stage(cur ^ 1, nc + 1);   // prefetch BEFORE compute
        const char* sEnB = lds + cur * 16384;
        const char* sPWB = lds + 65536 + cur * 32768;
        char* sSB = lds + 32768;
        // preload Pt fragments for the Z phase (depend only on sPW[cur])
        short8 pfr[4][4];
#pragma unroll
        for (int ks = 0; ks < 4; ++ks)
#pragma unroll
            for (int j = 0; j < 4; ++j) {
                int row = wc * 64 + j * 16 + lc;
                pfr[ks][j] = *(const short8*)(sPWB + row * 256 + SWZ(ks * 64 + quad * 16, row));
            }
        // S tile (SWAPPED): lane -> col=m (lc), row=n (quad*4+r); packed 8B store
#pragma unroll
        for (int jt = 0; jt < 4; ++jt) {
            int ncol = wc * 64 + jt * 16;
            int nrow = ncol + lc;
            short8 b0 = *(const short8*)(sEnB + nrow * 128 + SWZ(quad * 16, nrow));
            short8 b1 = *(const short8*)(sEnB + nrow * 128 + SWZ(64 + quad * 16, nrow));
#pragma unroll
            for (int i = 0; i < 2; ++i) {
                floatx4 s = (floatx4){0.f, 0.f, 0.f, 0.f};
                s = __builtin_amdgcn_mfma_f32_16x16x32_bf16(b0, ae[i][0], s, 0, 0, 0);
                s = __builtin_amdgcn_mfma_f32_16x16x32_bf16(b1, ae[i][1], s, 0, 0, 0);
                int mloc = wr * 32 + i * 16 + lc;
                int nbase = ncol + quad * 4;
                short4v pk;
#pragma unroll
                for (int r = 0; r < 4; ++r) {
                    float v = fmaxf(s[r], 0.f);
                    if (m0 + mloc == nc * 128 + nbase + r) v += 1.0f;
                    pk[r] = (short)f2bf(v);
                }
                *(short4v*)(sSB + mloc * 256 + SWZ(2 * nbase, mloc)) = pk;
            }
        }
        barrier_lds_only();                   // sS visible; prefetch stays in flight
        // Z (SWAPPED): acc[i][j] = Z^T frag; A=Pt (preloaded), B=S rows
#pragma unroll
        for (int ks = 0; ks < 4; ++ks) {
            short8 sfr[2];
#pragma unroll
            for (int i = 0; i < 2; ++i) {
                int row = wr * 32 + i * 16 + lc;
                sfr[i] = *(const short8*)(sSB + row * 256 + SWZ(ks * 64 + quad * 16, row));
            }
#pragma unroll
            for (int i = 0; i < 2; ++i)
#pragma unroll
                for (int j = 0; j < 4; ++j)
                    acc[i][j] = __builtin_amdgcn_mfma_f32_16x16x32_bf16(pfr[ks][j], sfr[i], acc[i][j], 0, 0, 0);
        }
        __syncthreads();                      // drain prefetch + all LDS reads
        cur ^= 1;
    }

    // ---- epilogue: Y = dinv*Z (packed 8B writes; acc holds Z^T)
    char* sYB = lds + 32768;
    char* sWB = lds + 65536;
    for (int i = 0; i < 2; ++i)
        for (int j = 0; j < 4; ++j) {
            int mloc = wr * 32 + i * 16 + lc;
            int dbase = wc * 64 + j * 16 + quad * 4;
            short4v pk;
            for (int r = 0; r < 4; ++r)
                pk[r] = (short)f2bf(acc[i][j][r] * dvm[i]);
            *(short4v*)(sYB + mloc * 256 + SWZ(2 * dbase, mloc)) = pk;
        }
    for (int it = 0; it < 4; ++it) {          // W fp32 -> bf16 LDS (swizzled write)
        int c = t + 512 * it;
        int row = c >> 4, colb = (c & 15) * 16;
        const float* p = Wf + row * DF + (c & 15) * 8;
        *(short8*)(sWB + row * 256 + SWZ(colb, row)) =
            cvt8(*(const float4*)p, *(const float4*)(p + 4));
    }
    __syncthreads();
    floatx4 accH[2][4];
    for (int i = 0; i < 2; ++i)
        for (int j = 0; j < 4; ++j) accH[i][j] = (floatx4){0.f, 0.f, 0.f, 0.f};
    for (int ks = 0; ks < 4; ++ks) {
        short8 afr[2], bfr[4];
        for (int i = 0; i < 2; ++i) {
            int row = wr * 32 + i * 16 + lc;
            afr[i] = *(const short8*)(sYB + row * 256 + SWZ(ks * 64 + quad * 16, row));
        }
        for (int j = 0; j < 4; ++j) {
            int row = wc * 64 + j * 16 + lc;
            bfr[j] = *(const short8*)(sWB + row * 256 + SWZ(ks * 64 + quad * 16, row));
        }
        for (int i = 0; i < 2; ++i)
            for (int j = 0; j < 4; ++j) {
                if (MODE == 2)                // swapped: lane holds 4 consecutive o per m
                    accH[i][j] = __builtin_amdgcn_mfma_f32_16x16x32_bf16(bfr[j], afr[i], accH[i][j], 0, 0, 0);
                else                          // unswapped: 4 consecutive m per o (packed sT)
                    accH[i][j] = __builtin_amdgcn_mfma_f32_16x16x32_bf16(afr[i], bfr[j], accH[i][j], 0, 0, 0);
            }
    }
    if (MODE == 2) {
        __syncthreads();                      // reuse lds as fp32 sF[128][132]
        float* sF = (float*)lds;
        for (int i = 0; i < 2; ++i)
            for (int j = 0; j < 4; ++j) {
                int mloc = wr * 32 + i * 16 + lc;
                int obase = wc * 64 + j * 16 + quad * 4;
                float4 f4;
                f4.x = fmaxf(accH[i][j][0], 0.f);
                f4.y = fmaxf(accH[i][j][1], 0.f);
                f4.z = fmaxf(accH[i][j][2], 0.f);
                f4.w = fmaxf(accH[i][j][3], 0.f);
                *(float4*)(&sF[mloc * 132 + obase]) = f4;
            }
        __syncthreads();
        float* Ob = OutF + ((size_t)b * M_ + m0) * DF;
        for (int it = 0; it < 8; ++it) {
            int c = t + 512 * it;             // 4096 = 128 rows x 32 float4
            int row = c >> 5, off = (c & 31) * 4;
            *(float4*)(Ob + (size_t)row * DF + off) = *(const float4*)(&sF[row * 132 + off]);
        }
    } else {
        __syncthreads();                      // reuse lds as sT [128 o][136] u16
        unsigned short* sT = (unsigned short*)lds;
        for (int i = 0; i < 2; ++i)
            for (int j = 0; j < 4; ++j) {
                int mrow = wr * 32 + i * 16 + quad * 4;
                int col = wc * 64 + j * 16 + lc;
                short4v pk;
                for (int r = 0; r < 4; ++r)
                    pk[r] = (short)f2bf(fmaxf(accH[i][j][r], 0.f) * dv[i][r]);
                *(short4v*)(&sT[col * 136 + mrow]) = pk;  // 8B write, mrow % 4 == 0
            }
        __syncthreads();
        for (int it = 0; it < 4; ++it) {
            int c = t + 512 * it;             // 2048 = 128 o-rows x 16
            int o = c >> 4, off = (c & 15) * 8;
            *(short8*)(OutT + (size_t)(b * DF + o) * M_ + m0 + off) =
                *(const short8*)(&sT[o * 136 + off]);
        }
    }
}

// ================================================================ fallback path (verified earlier)
__global__ __launch_bounds__(256) void cast_kernel(
    const float* __restrict__ E, const float* __restrict__ W1,
    const float* __restrict__ W2, unsigned short* __restrict__ Ebf,
    unsigned short* __restrict__ W1bf, unsigned short* __restrict__ W2bf) {
    const int NE = B_ * M_ * ED;          // 2,097,152
    const int NW = DF * DF;               // 16,384
    int idx = (blockIdx.x * 256 + threadIdx.x) * 4;
    const float* src; unsigned short* dst; int off;
    if (idx < NE)            { src = E;  dst = Ebf;  off = idx; }
    else if (idx < NE + NW)  { src = W1; dst = W1bf; off = idx - NE; }
    else                     { src = W2; dst = W2bf; off = idx - NE - NW; }
    float4 v = *(const float4*)(src + off);
    ushort4 o;
    o.x = f2bf(v.x); o.y = f2bf(v.y); o.z = f2bf(v.z); o.w = f2bf(v.w);
    *(ushort4*)(dst + off) = o;
}

__global__ __launch_bounds__(256) void degree_kernel(
    const unsigned short* __restrict__ Ebf, float* __restrict__ dinv) {
    int mt = blockIdx.x, b = blockIdx.y;
    int t = threadIdx.x;
    int w = t >> 6, lane = t & 63, quad = lane >> 4, lc = lane & 15;
    __shared__ unsigned short sEn[128][72];
    const unsigned short* Eb = Ebf + (size_t)b * M_ * ED;
    short8 afr[2][2];
    for (int i = 0; i < 2; ++i) {
        int row = mt * 128 + w * 32 + i * 16 + lc;
        for (int ks = 0; ks < 2; ++ks)
            afr[i][ks] = *(const short8*)(Eb + (size_t)row * ED + ks * 32 + quad * 8);
    }
    floatx4 rsum[2];
    rsum[0] = (floatx4){0.f,0.f,0.f,0.f};
    rsum[1] = (floatx4){0.f,0.f,0.f,0.f};
    for (int nc = 0; nc < 8; ++nc) {
        __syncthreads();
        for (int it = 0; it < 4; ++it) {
            int c = t + 256 * it;
            int row = c >> 3, off = (c & 7) * 8;
            *(short8*)(&sEn[row][off]) =
                *(const short8*)(Eb + (size_t)(nc * 128 + row) * ED + off);
        }
        __syncthreads();
        for (int nt = 0; nt < 8; ++nt) {
            short8 b0 = *(const short8*)(&sEn[nt * 16 + lc][quad * 8]);
            short8 b1 = *(const short8*)(&sEn[nt * 16 + lc][32 + quad * 8]);
            for (int i = 0; i < 2; ++i) {
                floatx4 s = (floatx4){0.f,0.f,0.f,0.f};
                s = __builtin_amdgcn_mfma_f32_16x16x32_bf16(afr[i][0], b0, s, 0, 0, 0);
                s = __builtin_amdgcn_mfma_f32_16x16x32_bf16(afr[i][1], b1, s, 0, 0, 0);
                for (int r = 0; r < 4; ++r) rsum[i][r] += fmaxf(s[r], 0.f);
            }
        }
    }
    for (int i = 0; i < 2; ++i)
        for (int r = 0; r < 4; ++r) {
            float v = rsum[i][r];
            v += __shfl_xor(v, 1, 16);
            v += __shfl_xor(v, 2, 16);
            v += __shfl_xor(v, 4, 16);
            v += __shfl_xor(v, 8, 16);
            if (lc == 0) {
                int row = mt * 128 + w * 32 + i * 16 + quad * 4 + r;
                dinv[b * M_ + row] = rsqrtf(1.0f + v);
            }
        }
}

__global__ __launch_bounds__(256) void tscale128_kernel(
    const float* __restrict__ X, const float* __restrict__ dinv,
    unsigned short* __restrict__ Xt) {
    int mt = blockIdx.x, b = blockIdx.y;
    int t = threadIdx.x;
    __shared__ unsigned short sT[128][136];
    int nloc = t >> 5;
    int d4 = (t & 31) * 4;
    for (int pass = 0; pass < 16; ++pass) {
        int n = pass * 8 + nloc;
        int grow = b * M_ + mt * 128 + n;
        float sc = dinv[grow];
        float4 v = *(const float4*)(X + (size_t)grow * DF + d4);
        sT[d4 + 0][n] = f2bf(v.x * sc);
        sT[d4 + 1][n] = f2bf(v.y * sc);
        sT[d4 + 2][n] = f2bf(v.z * sc);
        sT[d4 + 3][n] = f2bf(v.w * sc);
    }
    __syncthreads();
    for (int it = 0; it < 8; ++it) {
        int c = t + 256 * it;
        int d = c >> 4, off = (c & 15) * 8;
        *(short8*)(Xt + (size_t)(b * DF + d) * M_ + mt * 128 + off) =
            *(const short8*)(&sT[d][off]);
    }
}

template <int MODE>
__global__ __launch_bounds__(256) void gcn_kernel(
    const unsigned short* __restrict__ Ebf,
    const unsigned short* __restrict__ Pt,
    const unsigned short* __restrict__ Wbf,
    const float* __restrict__ dinv,
    unsigned short* __restrict__ OutT,
    float* __restrict__ OutF) {
    int mt = blockIdx.x, b = blockIdx.y;
    int t = threadIdx.x;
    int w = t >> 6, lane = t & 63, quad = lane >> 4, lc = lane & 15;
    int wr = w & 1, wc = w >> 1;
    __shared__ unsigned short sEn[128][72];
    __shared__ unsigned short sS[128][136];
    __shared__ unsigned short sPW[128][136];
    const unsigned short* Eb = Ebf + (size_t)b * M_ * ED;
    short8 ae[4][2];
    for (int i = 0; i < 4; ++i) {
        int row = mt * 128 + wr * 64 + i * 16 + lc;
        for (int ks = 0; ks < 2; ++ks)
            ae[i][ks] = *(const short8*)(Eb + (size_t)row * ED + ks * 32 + quad * 8);
    }
    floatx4 accZ[4][4];
    for (int i = 0; i < 4; ++i)
        for (int j = 0; j < 4; ++j) accZ[i][j] = (floatx4){0.f,0.f,0.f,0.f};
    for (int nc = 0; nc < 8; ++nc) {
        __syncthreads();
        for (int it = 0; it < 4; ++it) {
            int c = t + 256 * it;
            int row = c >> 3, off = (c & 7) * 8;
            *(short8*)(&sEn[row][off]) =
                *(const short8*)(Eb + (size_t)(nc * 128 + row) * ED + off);
        }
        for (int it = 0; it < 8; ++it) {
            int c = t + 256 * it;
            int drow = c >> 4, off = (c & 15) * 8;
            *(short8*)(&sPW[drow][off]) =
                *(const short8*)(Pt + (size_t)(b * DF + drow) * M_ + nc * 128 + off);
        }
        __syncthreads();
        for (int jt = 0; jt < 4; ++jt) {
            int ncol = wc * 64 + jt * 16;
            short8 b0 = *(const short8*)(&sEn[ncol + lc][quad * 8]);
            short8 b1 = *(const short8*)(&sEn[ncol + lc][32 + quad * 8]);
            for (int i = 0; i < 4; ++i) {
                floatx4 s = (floatx4){0.f,0.f,0.f,0.f};
                s = __builtin_amdgcn_mfma_f32_16x16x32_bf16(ae[i][0], b0, s, 0, 0, 0);
                s = __builtin_amdgcn_mfma_f32_16x16x32_bf16(ae[i][1], b1, s, 0, 0, 0);
                int mrow = wr * 64 + i * 16 + quad * 4;
                for (int r = 0; r < 4; ++r) {
                    float v = fmaxf(s[r], 0.f);
                    if (mt == nc && (mrow + r) == (ncol + lc)) v += 1.0f;
                    sS[mrow + r][ncol + lc] = f2bf(v);
                }
            }
        }
        __syncthreads();
        for (int ks = 0; ks < 4; ++ks) {
            short8 afr[4];
            for (int i = 0; i < 4; ++i)
                afr[i] = *(const short8*)(&sS[wr * 64 + i * 16 + lc][ks * 32 + quad * 8]);
            for (int j = 0; j < 4; ++j) {
                short8 bfr = *(const short8*)(&sPW[wc * 64 + j * 16 + lc][ks * 32 + quad * 8]);
                for (int i = 0; i < 4; ++i)
                    accZ[i][j] = __builtin_amdgcn_mfma_f32_16x16x32_bf16(afr[i], bfr, accZ[i][j], 0, 0, 0);
            }
        }
    }
    float dv[4][4];
    for (int i = 0; i < 4; ++i)
        for (int r = 0; r < 4; ++r)
            dv[i][r] = dinv[b * M_ + mt * 128 + wr * 64 + i * 16 + quad * 4 + r];
    __syncthreads();
    for (int i = 0; i < 4; ++i)
        for (int j = 0; j < 4; ++j) {
            int mrow = wr * 64 + i * 16 + quad * 4;
            int col = wc * 64 + j * 16 + lc;
            for (int r = 0; r < 4; ++r)
                sS[mrow + r][col] = f2bf(accZ[i][j][r] * dv[i][r]);
        }
    for (int it = 0; it < 8; ++it) {
        int c = t + 256 * it;
        int row = c >> 4, off = (c & 15) * 8;
        *(short8*)(&sPW[row][off]) = *(const short8*)(Wbf + row * DF + off);
    }
    __syncthreads();
    floatx4 accH[4][4];
    for (int i = 0; i < 4; ++i)
        for (int j = 0; j < 4; ++j) accH[i][j] = (floatx4){0.f,0.f,0.f,0.f};
    for (int ks = 0; ks < 4; ++ks) {
        short8 afr[4], bfr[4];
        for (int i = 0; i < 4; ++i)
            afr[i] = *(const short8*)(&sS[wr * 64 + i * 16 + lc][ks * 32 + quad * 8]);
        for (int j = 0; j < 4; ++j)
            bfr[j] = *(const short8*)(&sPW[wc * 64 + j * 16 + lc][ks * 32 + quad * 8]);
        for (int i = 0; i < 4; ++i)
            for (int j = 0; j < 4; ++j)
                accH[i][j] = __builtin_amdgcn_mfma_f32_16x16x32_bf16(afr[i], bfr[j], accH[i][j], 0, 0, 0);
    }
    if (MODE == 2) {
        float* Ob = OutF + ((size_t)b * M_ + mt * 128) * DF;
        for (int i = 0; i < 4; ++i)
            for (int j = 0; j < 4; ++j) {
                int mrow = wr * 64 + i * 16 + quad * 4;
                int col = wc * 64 + j * 16 + lc;
                for (int r = 0; r < 4; ++r)
                    Ob[(size_t)(mrow + r) * DF + col] = fmaxf(accH[i][j][r], 0.f);
            }
    } else {
        __syncthreads();
        for (int i = 0; i < 4; ++i)
            for (int j = 0; j < 4; ++j) {
                int mrow = wr * 64 + i * 16 + quad * 4;
                int col = wc * 64 + j * 16 + lc;
                for (int r = 0; r < 4; ++r)
                    sS[col][mrow + r] = f2bf(fmaxf(accH[i][j][r], 0.f) * dv[i][r]);
            }
        __syncthreads();
        unsigned short* Ob = OutT + (size_t)b * DF * M_ + mt * 128;
        for (int it = 0; it < 8; ++it) {
            int c = t + 256 * it;
            int orow = c >> 4, off = (c & 15) * 8;
            *(short8*)(Ob + (size_t)orow * M_ + off) = *(const short8*)(&sS[orow][off]);
        }
    }
}

// ---------------------------------------------------------------- launch
extern "C" void kernel_launch(void* const* d_in, const int* in_sizes, int n_in,
                              void* d_out, int out_size, void* d_ws, size_t ws_size,
                              hipStream_t stream) {
    (void)in_sizes; (void)n_in; (void)out_size;
    const float* X  = (const float*)d_in[0];
    const float* E  = (const float*)d_in[1];
    const float* W1 = (const float*)d_in[2];
    const float* W2 = (const float*)d_in[3];
    float* out = (float*)d_out;

    char* ws = (char*)d_ws;
    unsigned short* Ebf  = (unsigned short*)(ws);
    unsigned short* W1bf = (unsigned short*)(ws + 4194304);
    unsigned short* W2bf = (unsigned short*)(ws + 4227072);
    float*          dinv = (float*)(ws + 4259840);
    unsigned short* Xt   = (unsigned short*)(ws + 4390912);
    unsigned short* Ht   = (unsigned short*)(ws + 12779520);
    const size_t NEED = 21168128ull;

    if (ws_size >= NEED) {
        prep_kernel<<<dim3(32, 8), 512, 0, stream>>>(E, X, Ebf, dinv, Xt);
        layer_kernel<1><<<dim3(32, 8), 512, 0, stream>>>(Ebf, Xt, W1, dinv, Ht, nullptr);
        layer_kernel<2><<<dim3(32, 8), 512, 0, stream>>>(Ebf, Ht, W2, dinv, nullptr, out);
    } else {
        cast_kernel<<<2080, 256, 0, stream>>>(E, W1, W2, Ebf, W1bf, W2bf);
        degree_kernel<<<dim3(8, 32), 256, 0, stream>>>(Ebf, dinv);
        tscale128_kernel<<<dim3(8, 32), 256, 0, stream>>>(X, dinv, Xt);
        gcn_kernel<1><<<dim3(8, 32), 256, 0, stream>>>(Ebf, Xt, W1bf, dinv, Ht, nullptr);
        gcn_kernel<2><<<dim3(8, 32), 256, 0, stream>>>(Ebf, Ht, W2bf, dinv, nullptr, out);
    }
}